// Round 19
// baseline (309.804 us; speedup 1.0000x reference)
//
#include <hip/hip_runtime.h>
#include <math.h>

#define NN_   6000
#define EE_   192000
#define CIN_  32
#define CHID_ 64
#define KK_   125   // 5^3 spline kernel cells
#define EB_   32    // edge batch per block in build_T
#define CH1_  4     // x-GEMM outer chunks (each = CPB*128 cols)
#define CH2_  8     // h-GEMM outer chunks
#define CPB_  8     // k-chunks per GEMM block (128 cols each)

// fp32 -> bf16 round-to-nearest-even
static __device__ __forceinline__ unsigned short f2bf(float f) {
    unsigned int u = __builtin_bit_cast(unsigned int, f);
    u += 0x7fff + ((u >> 16) & 1);
    return (unsigned short)(u >> 16);
}
static __device__ __forceinline__ float bf2f(unsigned short h) {
    unsigned int u = ((unsigned int)h) << 16;
    return __builtin_bit_cast(float, u);
}

// ---------------------------------------------------------------------------
// Launch 1: deg count + weight packs (independent work, one launch).
// ---------------------------------------------------------------------------
#define PK1_ (192 * KK_ * CIN_)    // 768000
#define PK2_ (128 * KK_ * CHID_)   // 1024000
#define CB_  ((EE_ + 255) / 256)   // 750 count blocks
__global__ __launch_bounds__(256) void count_pack_kernel(
    const int* __restrict__ ei, int* __restrict__ deg,
    const float* __restrict__ W_xr, const float* __restrict__ W_xz,
    const float* __restrict__ W_xn, const float* __restrict__ W_hr,
    const float* __restrict__ W_hz,
    unsigned short* __restrict__ B1t, unsigned short* __restrict__ B2t)
{
    const int b = blockIdx.x;
    if (b < CB_) {
        int e = b * 256 + threadIdx.x;
        if (e < EE_) atomicAdd(&deg[ei[EE_ + e]], 1);
        return;
    }
    int gid = (b - CB_) * 256 + threadIdx.x;
    if (gid < PK1_) {
        int n  = gid / (KK_ * CIN_);
        int kk = gid % (KK_ * CIN_);
        int conv = n >> 6, o = n & 63;
        const float* W = (conv == 0) ? W_xr : ((conv == 1) ? W_xz : W_xn);
        B1t[gid] = f2bf(W[(size_t)kk * 64 + o]);
    } else if (gid < PK1_ + PK2_) {
        int g2 = gid - PK1_;
        int n  = g2 / (KK_ * CHID_);
        int kk = g2 % (KK_ * CHID_);
        int conv = n >> 6, o = n & 63;
        const float* W = (conv == 0) ? W_hr : W_hz;
        B2t[g2] = f2bf(W[(size_t)kk * 64 + o]);
    }
}

__global__ __launch_bounds__(1024) void scan_kernel(
    const int* __restrict__ deg, int* __restrict__ offs, int* __restrict__ cursor)
{
    __shared__ int part[1024];
    const int tid = threadIdx.x;
    const int CH = (NN_ + 1023) / 1024;   // 6
    const int base = tid * CH;
    int loc[CH];
    int s = 0;
#pragma unroll
    for (int i = 0; i < CH; ++i) {
        int v = (base + i < NN_) ? deg[base + i] : 0;
        loc[i] = s; s += v;
    }
    part[tid] = s;
    __syncthreads();
    for (int off = 1; off < 1024; off <<= 1) {
        int v = (tid >= off) ? part[tid - off] : 0;
        __syncthreads();
        part[tid] += v;
        __syncthreads();
    }
    const int pre = (tid > 0) ? part[tid - 1] : 0;
#pragma unroll
    for (int i = 0; i < CH; ++i) {
        if (base + i < NN_) {
            offs[base + i]   = pre + loc[i];
            cursor[base + i] = pre + loc[i];
        }
    }
    if (tid == 1023) offs[NN_] = part[1023];
}

// Compute per-edge spline meta ONCE, scattered to dst-sorted position.
__global__ __launch_bounds__(256) void prep_kernel(
    const int* __restrict__ ei, const float* __restrict__ attr,
    int* __restrict__ cursor, float4* __restrict__ meta_s, int* __restrict__ src_s)
{
    int e = blockIdx.x * 256 + threadIdx.x;
    if (e >= EE_) return;
    const int dst = ei[EE_ + e];
    const int p   = atomicAdd(&cursor[dst], 1);
    float f[3]; int i0[3];
#pragma unroll
    for (int d = 0; d < 3; ++d) {
        float u  = attr[e * 3 + d] * 4.0f;
        float fl = floorf(u);
        fl = fminf(fmaxf(fl, 0.0f), 3.0f);
        i0[d] = (int)fl;
        f[d]  = u - fl;
    }
    meta_s[p] = make_float4(f[0], f[1], f[2],
        __int_as_float(i0[0] * 25 + i0[1] * 5 + i0[2]));
    src_s[p] = ei[e];
}

// ---------------------------------------------------------------------------
// Per-node T build (R16-proven; separate kernels so LDS is per-C sized).
// Non-atomic b64 LDS RMW; packed-bf16 feat staging.
// ---------------------------------------------------------------------------
template<int C>
__global__ __launch_bounds__(256) void build_T_kernel(
    const float4* __restrict__ meta_s, const int* __restrict__ src_s,
    const float* __restrict__ feat, const int* __restrict__ offs,
    unsigned short* __restrict__ Tb)
{
    constexpr int PAD   = C + 2;
    constexpr int NPAIR = C / 2;
    constexpr int EPI   = (C == 32) ? 2 : 1;     // edges per iteration
    constexpr int PPW   = (C == 32) ? 4 : 8;     // pairs owned per wave
    __shared__ float        Tl[KK_ * PAD];
    __shared__ float4       s_meta[EB_];
    __shared__ int          s_src[EB_];
    __shared__ unsigned int s_fb[EB_ * NPAIR];   // packed bf16 pairs

    const int node = blockIdx.x;
    const int tid  = threadIdx.x;
    const int wave = tid >> 6;
    const int lane = tid & 63;

    for (int i = tid; i < KK_ * PAD; i += 256) Tl[i] = 0.f;

    const int j0 = offs[node], j1 = offs[node + 1];

    const int e2   = (EPI == 2) ? (lane >> 5) : 0;
    const int s_c  = (EPI == 2) ? ((lane >> 2) & 7) : (lane >> 3);
    const int pl   = (EPI == 2) ? (lane & 3) : (lane & 7);
    const int pidx = wave * PPW + pl;
    const int cb0 = s_c & 1, cb1 = (s_c >> 1) & 1, cb2 = (s_c >> 2) & 1;
    const int offc = cb0 * 25 + cb1 * 5 + cb2;

    __syncthreads();

    for (int jb = j0; jb < j1; jb += EB_) {
        const int m = min(EB_, j1 - jb);

        if (tid < m) {
            s_meta[tid] = meta_s[jb + tid];
            s_src[tid]  = src_s[jb + tid];
        }
        __syncthreads();

        for (int u = tid; u < m * NPAIR; u += 256) {
            const int r = u / NPAIR, q = u % NPAIR;
            float2 v = *(const float2*)&feat[(size_t)s_src[r] * C + 2 * q];
            s_fb[u] = (unsigned int)f2bf(v.x) | ((unsigned int)f2bf(v.y) << 16);
        }
        __syncthreads();

        for (int eb = 0; eb < m; eb += EPI) {
            const int e = eb + e2;
            if (EPI == 1 || e < m) {
                const float4 mt = s_meta[e];
                const int base  = __float_as_int(mt.w);
                const float p = (cb0 ? mt.x : 1.f - mt.x) *
                                (cb1 ? mt.y : 1.f - mt.y) *
                                (cb2 ? mt.z : 1.f - mt.z);
                const unsigned int fp = s_fb[e * NPAIR + pidx];
                const float fx = bf2f((unsigned short)(fp & 0xffff));
                const float fy = bf2f((unsigned short)(fp >> 16));
                float* cell = &Tl[(base + offc) * PAD + 2 * pidx];
                cell[0] += p * fx;
                cell[1] += p * fy;
            }
        }
        __syncthreads();
    }

    unsigned int* To = (unsigned int*)(Tb + (size_t)node * (KK_ * C));
    for (int u = tid; u < KK_ * NPAIR; u += 256) {
        int k = u / NPAIR, pp = u % NPAIR;
        unsigned int lo = f2bf(Tl[k * PAD + 2 * pp]);
        unsigned int hi = f2bf(Tl[k * PAD + 2 * pp + 1]);
        To[u] = lo | (hi << 16);
    }
}

// ---------------------------------------------------------------------------
// GEMM body v6: barrier-free inner K-loop + CROSS-CHUNK A-PREFETCH.
// Chunk cc+1's A-fragments are issued during chunk cc's MFMA phase, hiding
// the ~900cyc HBM A-load latency behind compute + barriers + B-stage.
// B is NOT double-buffered: it's L2-resident (~200cyc) and +64 VGPR would
// cost occupancy (R12/R14 lesson).
// ---------------------------------------------------------------------------
template<int NT, int NTF, int CPB>
static __device__ __forceinline__ void gemm_body(
    unsigned char* arena,
    const unsigned short* __restrict__ A, const unsigned short* __restrict__ Bt,
    unsigned short* __restrict__ P, int M, int Kd, int chunk, int zhalf)
{
    constexpr int SPC   = 4;
    constexpr int COLS  = SPC * 32;       // 128
    constexpr int BP    = COLS + 8;       // 136 shorts
    constexpr int NFRAG = NT / 16;
    constexpr int CSP   = NT + 8;
    unsigned short (*Bs)[BP] = (unsigned short(*)[BP])arena;

    using bf16x8 = __attribute__((ext_vector_type(8))) short;
    using f32x4  = __attribute__((ext_vector_type(4))) float;

    const int tid  = threadIdx.x;
    const int wave = tid >> 6;
    const int lane = tid & 63;
    const int quad = lane >> 4;
    const int l16  = lane & 15;
    const int m0   = blockIdx.x * 64;
    const unsigned short* Bp = Bt + (size_t)zhalf * NT * Kd;

    const int  arow   = m0 + wave * 16 + l16;
    const bool avalid = arow < M;
    const unsigned short* Ap = A + (size_t)(avalid ? arow : 0) * Kd;

    f32x4 acc[NFRAG];
#pragma unroll
    for (int f = 0; f < NFRAG; ++f) acc[f] = (f32x4){0.f, 0.f, 0.f, 0.f};

    const int kbase = chunk * CPB * COLS;

    // preload chunk 0's A-fragments
    uint4 afr[SPC];
#pragma unroll
    for (int s = 0; s < SPC; ++s) {
        const int k = kbase + s * 32 + quad * 8;
        afr[s] = (avalid && k < Kd) ? *(const uint4*)(Ap + k)
                                    : make_uint4(0u, 0u, 0u, 0u);
    }

    for (int cc = 0; cc < CPB; ++cc) {
        const int k0 = kbase + cc * COLS;
        if (k0 >= Kd) break;
        const int ksz = min(Kd - k0, COLS);

        __syncthreads();   // previous chunk's LDS reads complete

        // stage B-chunk to LDS (L2-resident, short latency)
        constexpr int BUNITS = NT * COLS / 8;
        for (int u = tid; u < BUNITS; u += 256) {
            const int row = u / (COLS / 8);
            const int cq  = (u % (COLS / 8)) * 8;
            uint4 v = make_uint4(0u, 0u, 0u, 0u);
            if (cq < ksz) v = *(const uint4*)(Bp + (size_t)row * Kd + k0 + cq);
            *(uint4*)&Bs[row][cq] = v;
        }

        __syncthreads();   // B ready

        // prefetch NEXT chunk's A-fragments (in flight during MFMA below)
        uint4 afr_n[SPC];
        const int k0n = k0 + COLS;
#pragma unroll
        for (int s = 0; s < SPC; ++s) {
            const int k = k0n + s * 32 + quad * 8;
            afr_n[s] = (cc + 1 < CPB && avalid && k < Kd)
                         ? *(const uint4*)(Ap + k)
                         : make_uint4(0u, 0u, 0u, 0u);
        }

        // barrier-free MFMA loop on current A-fragments (already resident)
#pragma unroll
        for (int s = 0; s < SPC; ++s) {
            bf16x8 af = __builtin_bit_cast(bf16x8, afr[s]);
#pragma unroll
            for (int f = 0; f < NFRAG; ++f) {
                bf16x8 bfv = *(bf16x8*)&Bs[f * 16 + l16][s * 32 + quad * 8];
                acc[f] = __builtin_amdgcn_mfma_f32_16x16x32_bf16(af, bfv, acc[f], 0, 0, 0);
            }
        }
#pragma unroll
        for (int s = 0; s < SPC; ++s) afr[s] = afr_n[s];
    }

    // stage C-tile (bf16) in LDS over Bs, full-line coalesced copy out
    __syncthreads();
    unsigned short* Cs = (unsigned short*)arena;   // [64][CSP]
    const int rbase = wave * 16 + quad * 4;
#pragma unroll
    for (int f = 0; f < NFRAG; ++f) {
        const int col = f * 16 + l16;
#pragma unroll
        for (int r = 0; r < 4; ++r)
            Cs[(rbase + r) * CSP + col] = f2bf(acc[f][r]);
    }
    __syncthreads();
    unsigned short* Pc = P + ((size_t)chunk * M + m0) * NTF + zhalf * NT;
    constexpr int UNITS = 64 * NT / 8;
    for (int u = tid; u < UNITS; u += 256) {
        const int row = (u * 8) / NT, col = (u * 8) % NT;
        if (m0 + row < M)
            *(uint4*)&Pc[(size_t)row * NTF + col] = *(const uint4*)&Cs[row * CSP + col];
    }
}

// Merged GEMM (R17-proven win): blockIdx.y < CH2_ -> h-chunk; else x-(chunk,half).
__global__ __launch_bounds__(256) void gemm_all_kernel(
    const unsigned short* __restrict__ Tx, const unsigned short* __restrict__ B1t,
    unsigned short* __restrict__ P1,
    const unsigned short* __restrict__ Th, const unsigned short* __restrict__ B2t,
    unsigned short* __restrict__ P2)
{
    __shared__ __align__(16) unsigned char arena[128 * 136 * 2];
    const int y = blockIdx.y;
    if (y < CH2_) {
        gemm_body<128, 128, CPB_>(arena, Th, B2t, P2, NN_, KK_ * CHID_, y, 0);
    } else {
        const int g = y - CH2_;            // 0..7 -> (chunk 0..3, half 0..1)
        gemm_body<96, 192, CPB_>(arena, Tx, B1t, P1, NN_, KK_ * CIN_, g >> 1, g & 1);
    }
}

// ---------------------------------------------------------------------------
// Epilogue: one wave per node, lane = output channel. Sums bf16 split-K
// partials (L2-resident), mean-agg, root GEMV, GRU gates.
// ---------------------------------------------------------------------------
__global__ __launch_bounds__(256) void epilogue_kernel(
    const unsigned short* __restrict__ P1, const unsigned short* __restrict__ P2,
    const int* __restrict__ offs,
    const float* __restrict__ x, const float* __restrict__ hidden,
    const float* __restrict__ root_xr, const float* __restrict__ root_hr,
    const float* __restrict__ root_xz, const float* __restrict__ root_hz,
    const float* __restrict__ root_xn,
    const float* __restrict__ b_xr, const float* __restrict__ b_hr,
    const float* __restrict__ b_xz, const float* __restrict__ b_hz,
    const float* __restrict__ b_xn,
    float* __restrict__ out)
{
    __shared__ float xsh[4][32];
    __shared__ float hsh[4][64];
    const int w = threadIdx.x >> 6;
    const int o = threadIdx.x & 63;
    const int m = blockIdx.x * 4 + w;
    if (m >= NN_) return;

    if (o < 32) xsh[w][o] = x[(size_t)m * 32 + o];
    const float hval = hidden[(size_t)m * 64 + o];
    hsh[w][o] = hval;

    float axr = 0.f, axz = 0.f, axn = 0.f;
#pragma unroll
    for (int c = 0; c < CH1_; ++c) {
        const unsigned short* p = P1 + ((size_t)c * NN_ + m) * 192;
        axr += bf2f(p[o]); axz += bf2f(p[64 + o]); axn += bf2f(p[128 + o]);
    }
    float ahr = 0.f, ahz = 0.f;
#pragma unroll
    for (int c = 0; c < CH2_; ++c) {
        const unsigned short* p = P2 + ((size_t)c * NN_ + m) * 128;
        ahr += bf2f(p[o]); ahz += bf2f(p[64 + o]);
    }

    const int   dg   = offs[m + 1] - offs[m];
    const float dinv = 1.0f / fmaxf((float)dg, 1.0f);
    axr *= dinv; axz *= dinv; axn *= dinv; ahr *= dinv; ahz *= dinv;

    float sxr = 0.f, sxz = 0.f, sxn = 0.f;
#pragma unroll
    for (int c = 0; c < CIN_; ++c) {
        float xv = xsh[w][c];
        sxr += xv * root_xr[c * 64 + o];
        sxz += xv * root_xz[c * 64 + o];
        sxn += xv * root_xn[c * 64 + o];
    }
    float shr = 0.f, shz = 0.f;
#pragma unroll
    for (int c = 0; c < CHID_; ++c) {
        float hv = hsh[w][c];
        shr += hv * root_hr[c * 64 + o];
        shz += hv * root_hz[c * 64 + o];
    }

    const float conv_xr = axr + sxr + b_xr[o];
    const float conv_xz = axz + sxz + b_xz[o];
    const float conv_xn = axn + sxn + b_xn[o];
    const float hr_out  = ahr + shr + b_hr[o];
    const float conv_hz = ahz + shz + b_hz[o];

    const float rg = 1.0f / (1.0f + expf(-(conv_xr + hr_out)));
    const float zg = 1.0f / (1.0f + expf(-(conv_xz + conv_hz)));
    const float ng = tanhf(conv_xn + rg * hr_out);
    out[(size_t)m * 64 + o] = (1.0f - zg) * ng + zg * hval;
}

// ---------------------------------------------------------------------------
extern "C" void kernel_launch(void* const* d_in, const int* in_sizes, int n_in,
                              void* d_out, int out_size, void* d_ws, size_t ws_size,
                              hipStream_t stream)
{
    const float* x       = (const float*)d_in[0];
    const float* hidden  = (const float*)d_in[1];
    const int*   ei      = (const int*)  d_in[2];
    const float* attr    = (const float*)d_in[3];
    const float* W_xr    = (const float*)d_in[4];
    const float* root_xr = (const float*)d_in[5];
    const float* b_xr    = (const float*)d_in[6];
    const float* W_hr    = (const float*)d_in[7];
    const float* root_hr = (const float*)d_in[8];
    const float* b_hr    = (const float*)d_in[9];
    const float* W_xz    = (const float*)d_in[10];
    const float* root_xz = (const float*)d_in[11];
    const float* b_xz    = (const float*)d_in[12];
    const float* W_hz    = (const float*)d_in[13];
    const float* root_hz = (const float*)d_in[14];
    const float* b_hz    = (const float*)d_in[15];
    const float* W_xn    = (const float*)d_in[16];
    const float* root_xn = (const float*)d_in[17];
    const float* b_xn    = (const float*)d_in[18];
    // d_in[19..21] (W_hn/root_hn/b_hn) are dead: reference reuses hr_out.
    float* out = (float*)d_out;

    // Workspace (~175 MB). No aliasing (gemm-x reads Tx while gemm-h writes
    // P2 concurrently inside gemm_all).
    char* w = (char*)d_ws;
    unsigned short* Tx  = (unsigned short*)w; w += (size_t)NN_ * KK_ * CIN_  * 2;  // 48 MB
    unsigned short* Th  = (unsigned short*)w; w += (size_t)NN_ * KK_ * CHID_ * 2;  // 96 MB
    unsigned short* B1t = (unsigned short*)w; w += (size_t)192 * KK_ * CIN_  * 2;  // 1.5 MB
    unsigned short* B2t = (unsigned short*)w; w += (size_t)128 * KK_ * CHID_ * 2;  // 2.0 MB
    unsigned short* P1  = (unsigned short*)w; w += (size_t)CH1_ * NN_ * 192 * 2;   // 9.2 MB
    unsigned short* P2  = (unsigned short*)w; w += (size_t)CH2_ * NN_ * 128 * 2;   // 12.3 MB
    float4* meta_s = (float4*)w; w += (size_t)EE_ * 16;                            // 3.07 MB
    int* src_s  = (int*)w;   w += (size_t)EE_ * 4;                                 // 0.77 MB
    int* deg    = (int*)w;   w += (size_t)NN_ * 4;
    int* offs   = (int*)w;   w += (size_t)(NN_ + 4) * 4;
    int* cursor = (int*)w;   w += (size_t)NN_ * 4;

    const int MT = (NN_ + 63) / 64;   // 94 m-tiles

    hipMemsetAsync(deg, 0, (size_t)NN_ * 4, stream);

    // ---- launch 1: deg count + weight packs (independent, merged) ----
    const int PACKB = (PK1_ + PK2_ + 255) / 256;
    count_pack_kernel<<<CB_ + PACKB, 256, 0, stream>>>(
        ei, deg, W_xr, W_xz, W_xn, W_hr, W_hz, B1t, B2t);

    // ---- scan + sorted edge records ----
    scan_kernel<<<1, 1024, 0, stream>>>(deg, offs, cursor);
    prep_kernel<<<(EE_ + 255) / 256, 256, 0, stream>>>(ei, attr, cursor, meta_s, src_s);

    // ---- T builds: separate kernels so LDS arena is per-C sized ----
    build_T_kernel<CHID_><<<NN_, 256, 0, stream>>>(meta_s, src_s, hidden, offs, Th);
    build_T_kernel<CIN_><<<NN_, 256, 0, stream>>>(meta_s, src_s, x, offs, Tx);

    // ---- merged x+h GEMMs (co-resident, A-prefetch pipelined) ----
    gemm_all_kernel<<<dim3(MT, CH2_ + 2 * CH1_), 256, 0, stream>>>(
        Tx, B1t, P1, Th, B2t, P2);

    // ---- fused reduce + GRU epilogue (wave per node) ----
    epilogue_kernel<<<(NN_ + 3) / 4, 256, 0, stream>>>(
        P1, P2, offs, x, hidden,
        root_xr, root_hr, root_xz, root_hz, root_xn,
        b_xr, b_hr, b_xz, b_hz, b_xn, out);
}

// Round 20
// 298.632 us; speedup vs baseline: 1.0374x; 1.0374x over previous
//
#include <hip/hip_runtime.h>
#include <math.h>

#define NN_   6000
#define EE_   192000
#define CIN_  32
#define CHID_ 64
#define KK_   125   // 5^3 spline kernel cells
#define EB_   32    // edge batch per block in build_T
#define CH1_  4     // x-GEMM outer chunks (each = CPB*128 cols)
#define CH2_  8     // h-GEMM outer chunks
#define CPB_  8     // k-chunks per GEMM block (128 cols each)

// fp32 -> bf16 round-to-nearest-even
static __device__ __forceinline__ unsigned short f2bf(float f) {
    unsigned int u = __builtin_bit_cast(unsigned int, f);
    u += 0x7fff + ((u >> 16) & 1);
    return (unsigned short)(u >> 16);
}
static __device__ __forceinline__ float bf2f(unsigned short h) {
    unsigned int u = ((unsigned int)h) << 16;
    return __builtin_bit_cast(float, u);
}

// ---------------------------------------------------------------------------
// Launch 1: deg count + weight packs (independent work, one launch).
// ---------------------------------------------------------------------------
#define PK1_ (192 * KK_ * CIN_)    // 768000
#define PK2_ (128 * KK_ * CHID_)   // 1024000
#define CB_  ((EE_ + 255) / 256)   // 750 count blocks
__global__ __launch_bounds__(256) void count_pack_kernel(
    const int* __restrict__ ei, int* __restrict__ deg,
    const float* __restrict__ W_xr, const float* __restrict__ W_xz,
    const float* __restrict__ W_xn, const float* __restrict__ W_hr,
    const float* __restrict__ W_hz,
    unsigned short* __restrict__ B1t, unsigned short* __restrict__ B2t)
{
    const int b = blockIdx.x;
    if (b < CB_) {
        int e = b * 256 + threadIdx.x;
        if (e < EE_) atomicAdd(&deg[ei[EE_ + e]], 1);
        return;
    }
    int gid = (b - CB_) * 256 + threadIdx.x;
    if (gid < PK1_) {
        int n  = gid / (KK_ * CIN_);
        int kk = gid % (KK_ * CIN_);
        int conv = n >> 6, o = n & 63;
        const float* W = (conv == 0) ? W_xr : ((conv == 1) ? W_xz : W_xn);
        B1t[gid] = f2bf(W[(size_t)kk * 64 + o]);
    } else if (gid < PK1_ + PK2_) {
        int g2 = gid - PK1_;
        int n  = g2 / (KK_ * CHID_);
        int kk = g2 % (KK_ * CHID_);
        int conv = n >> 6, o = n & 63;
        const float* W = (conv == 0) ? W_hr : W_hz;
        B2t[g2] = f2bf(W[(size_t)kk * 64 + o]);
    }
}

__global__ __launch_bounds__(1024) void scan_kernel(
    const int* __restrict__ deg, int* __restrict__ offs, int* __restrict__ cursor)
{
    __shared__ int part[1024];
    const int tid = threadIdx.x;
    const int CH = (NN_ + 1023) / 1024;   // 6
    const int base = tid * CH;
    int loc[CH];
    int s = 0;
#pragma unroll
    for (int i = 0; i < CH; ++i) {
        int v = (base + i < NN_) ? deg[base + i] : 0;
        loc[i] = s; s += v;
    }
    part[tid] = s;
    __syncthreads();
    for (int off = 1; off < 1024; off <<= 1) {
        int v = (tid >= off) ? part[tid - off] : 0;
        __syncthreads();
        part[tid] += v;
        __syncthreads();
    }
    const int pre = (tid > 0) ? part[tid - 1] : 0;
#pragma unroll
    for (int i = 0; i < CH; ++i) {
        if (base + i < NN_) {
            offs[base + i]   = pre + loc[i];
            cursor[base + i] = pre + loc[i];
        }
    }
    if (tid == 1023) offs[NN_] = part[1023];
}

// Compute per-edge spline meta ONCE, scattered to dst-sorted position.
__global__ __launch_bounds__(256) void prep_kernel(
    const int* __restrict__ ei, const float* __restrict__ attr,
    int* __restrict__ cursor, float4* __restrict__ meta_s, int* __restrict__ src_s)
{
    int e = blockIdx.x * 256 + threadIdx.x;
    if (e >= EE_) return;
    const int dst = ei[EE_ + e];
    const int p   = atomicAdd(&cursor[dst], 1);
    float f[3]; int i0[3];
#pragma unroll
    for (int d = 0; d < 3; ++d) {
        float u  = attr[e * 3 + d] * 4.0f;
        float fl = floorf(u);
        fl = fminf(fmaxf(fl, 0.0f), 3.0f);
        i0[d] = (int)fl;
        f[d]  = u - fl;
    }
    meta_s[p] = make_float4(f[0], f[1], f[2],
        __int_as_float(i0[0] * 25 + i0[1] * 5 + i0[2]));
    src_s[p] = ei[e];
}

// ---------------------------------------------------------------------------
// Per-node T build (R16-proven; separate kernels so LDS is per-C sized:
// x-pass 19.5 KB -> 8 blocks/CU, h-pass 37.9 KB -> 4 blocks/CU).
// Non-atomic b64 LDS RMW; packed-bf16 feat staging.
// ---------------------------------------------------------------------------
template<int C>
__global__ __launch_bounds__(256) void build_T_kernel(
    const float4* __restrict__ meta_s, const int* __restrict__ src_s,
    const float* __restrict__ feat, const int* __restrict__ offs,
    unsigned short* __restrict__ Tb)
{
    constexpr int PAD   = C + 2;
    constexpr int NPAIR = C / 2;
    constexpr int EPI   = (C == 32) ? 2 : 1;     // edges per iteration
    constexpr int PPW   = (C == 32) ? 4 : 8;     // pairs owned per wave
    __shared__ float        Tl[KK_ * PAD];
    __shared__ float4       s_meta[EB_];
    __shared__ int          s_src[EB_];
    __shared__ unsigned int s_fb[EB_ * NPAIR];   // packed bf16 pairs

    const int node = blockIdx.x;
    const int tid  = threadIdx.x;
    const int wave = tid >> 6;
    const int lane = tid & 63;

    for (int i = tid; i < KK_ * PAD; i += 256) Tl[i] = 0.f;

    const int j0 = offs[node], j1 = offs[node + 1];

    const int e2   = (EPI == 2) ? (lane >> 5) : 0;
    const int s_c  = (EPI == 2) ? ((lane >> 2) & 7) : (lane >> 3);
    const int pl   = (EPI == 2) ? (lane & 3) : (lane & 7);
    const int pidx = wave * PPW + pl;
    const int cb0 = s_c & 1, cb1 = (s_c >> 1) & 1, cb2 = (s_c >> 2) & 1;
    const int offc = cb0 * 25 + cb1 * 5 + cb2;

    __syncthreads();

    for (int jb = j0; jb < j1; jb += EB_) {
        const int m = min(EB_, j1 - jb);

        if (tid < m) {
            s_meta[tid] = meta_s[jb + tid];
            s_src[tid]  = src_s[jb + tid];
        }
        __syncthreads();

        for (int u = tid; u < m * NPAIR; u += 256) {
            const int r = u / NPAIR, q = u % NPAIR;
            float2 v = *(const float2*)&feat[(size_t)s_src[r] * C + 2 * q];
            s_fb[u] = (unsigned int)f2bf(v.x) | ((unsigned int)f2bf(v.y) << 16);
        }
        __syncthreads();

        for (int eb = 0; eb < m; eb += EPI) {
            const int e = eb + e2;
            if (EPI == 1 || e < m) {
                const float4 mt = s_meta[e];
                const int base  = __float_as_int(mt.w);
                const float p = (cb0 ? mt.x : 1.f - mt.x) *
                                (cb1 ? mt.y : 1.f - mt.y) *
                                (cb2 ? mt.z : 1.f - mt.z);
                const unsigned int fp = s_fb[e * NPAIR + pidx];
                const float fx = bf2f((unsigned short)(fp & 0xffff));
                const float fy = bf2f((unsigned short)(fp >> 16));
                float* cell = &Tl[(base + offc) * PAD + 2 * pidx];
                cell[0] += p * fx;
                cell[1] += p * fy;
            }
        }
        __syncthreads();
    }

    unsigned int* To = (unsigned int*)(Tb + (size_t)node * (KK_ * C));
    for (int u = tid; u < KK_ * NPAIR; u += 256) {
        int k = u / NPAIR, pp = u % NPAIR;
        unsigned int lo = f2bf(Tl[k * PAD + 2 * pp]);
        unsigned int hi = f2bf(Tl[k * PAD + 2 * pp + 1]);
        To[u] = lo | (hi << 16);
    }
}

// ---------------------------------------------------------------------------
// GEMM body (R18-proven, A-prefetch REVERTED: R19's cross-chunk prefetch
// raised VGPR 68->124 and the compiler's vmcnt(0) drain serialized the
// prefetch in front of the MFMA phase -- 61->76 us regression, per the
// documented source-level-pipelining failure mode).
// Barrier-free inner K-loop, multi-chunk blocks, COLS=128.
// ---------------------------------------------------------------------------
template<int NT, int NTF, int CPB>
static __device__ __forceinline__ void gemm_body(
    unsigned char* arena,
    const unsigned short* __restrict__ A, const unsigned short* __restrict__ Bt,
    unsigned short* __restrict__ P, int M, int Kd, int chunk, int zhalf)
{
    constexpr int SPC   = 4;
    constexpr int COLS  = SPC * 32;       // 128
    constexpr int BP    = COLS + 8;       // 136 shorts
    constexpr int NFRAG = NT / 16;
    constexpr int CSP   = NT + 8;
    unsigned short (*Bs)[BP] = (unsigned short(*)[BP])arena;

    using bf16x8 = __attribute__((ext_vector_type(8))) short;
    using f32x4  = __attribute__((ext_vector_type(4))) float;

    const int tid  = threadIdx.x;
    const int wave = tid >> 6;
    const int lane = tid & 63;
    const int quad = lane >> 4;
    const int l16  = lane & 15;
    const int m0   = blockIdx.x * 64;
    const unsigned short* Bp = Bt + (size_t)zhalf * NT * Kd;

    const int  arow   = m0 + wave * 16 + l16;
    const bool avalid = arow < M;
    const unsigned short* Ap = A + (size_t)(avalid ? arow : 0) * Kd;

    f32x4 acc[NFRAG];
#pragma unroll
    for (int f = 0; f < NFRAG; ++f) acc[f] = (f32x4){0.f, 0.f, 0.f, 0.f};

    for (int cc = 0; cc < CPB; ++cc) {
        const int k0 = (chunk * CPB + cc) * COLS;
        if (k0 >= Kd) break;
        const int ksz = min(Kd - k0, COLS);

        __syncthreads();

        constexpr int BUNITS = NT * COLS / 8;
        for (int u = tid; u < BUNITS; u += 256) {
            const int row = u / (COLS / 8);
            const int cq  = (u % (COLS / 8)) * 8;
            uint4 v = make_uint4(0u, 0u, 0u, 0u);
            if (cq < ksz) v = *(const uint4*)(Bp + (size_t)row * Kd + k0 + cq);
            *(uint4*)&Bs[row][cq] = v;
        }

        uint4 afr[SPC];
#pragma unroll
        for (int s = 0; s < SPC; ++s) {
            const int k = k0 + s * 32 + quad * 8;
            afr[s] = (avalid && k < Kd) ? *(const uint4*)(Ap + k)
                                        : make_uint4(0u, 0u, 0u, 0u);
        }

        __syncthreads();

#pragma unroll
        for (int s = 0; s < SPC; ++s) {
            bf16x8 af = __builtin_bit_cast(bf16x8, afr[s]);
#pragma unroll
            for (int f = 0; f < NFRAG; ++f) {
                bf16x8 bfv = *(bf16x8*)&Bs[f * 16 + l16][s * 32 + quad * 8];
                acc[f] = __builtin_amdgcn_mfma_f32_16x16x32_bf16(af, bfv, acc[f], 0, 0, 0);
            }
        }
    }

    __syncthreads();
    unsigned short* Cs = (unsigned short*)arena;   // [64][CSP]
    const int rbase = wave * 16 + quad * 4;
#pragma unroll
    for (int f = 0; f < NFRAG; ++f) {
        const int col = f * 16 + l16;
#pragma unroll
        for (int r = 0; r < 4; ++r)
            Cs[(rbase + r) * CSP + col] = f2bf(acc[f][r]);
    }
    __syncthreads();
    unsigned short* Pc = P + ((size_t)chunk * M + m0) * NTF + zhalf * NT;
    constexpr int UNITS = 64 * NT / 8;
    for (int u = tid; u < UNITS; u += 256) {
        const int row = (u * 8) / NT, col = (u * 8) % NT;
        if (m0 + row < M)
            *(uint4*)&Pc[(size_t)row * NTF + col] = *(const uint4*)&Cs[row * CSP + col];
    }
}

// Merged GEMM (R17-proven win): blockIdx.y < CH2_ -> h-chunk; else x-(chunk,half).
__global__ __launch_bounds__(256) void gemm_all_kernel(
    const unsigned short* __restrict__ Tx, const unsigned short* __restrict__ B1t,
    unsigned short* __restrict__ P1,
    const unsigned short* __restrict__ Th, const unsigned short* __restrict__ B2t,
    unsigned short* __restrict__ P2)
{
    __shared__ __align__(16) unsigned char arena[128 * 136 * 2];
    const int y = blockIdx.y;
    if (y < CH2_) {
        gemm_body<128, 128, CPB_>(arena, Th, B2t, P2, NN_, KK_ * CHID_, y, 0);
    } else {
        const int g = y - CH2_;            // 0..7 -> (chunk 0..3, half 0..1)
        gemm_body<96, 192, CPB_>(arena, Tx, B1t, P1, NN_, KK_ * CIN_, g >> 1, g & 1);
    }
}

// ---------------------------------------------------------------------------
// Epilogue: one wave per node, lane = output channel. Sums bf16 split-K
// partials (L2-resident), mean-agg, root GEMV, GRU gates.
// ---------------------------------------------------------------------------
__global__ __launch_bounds__(256) void epilogue_kernel(
    const unsigned short* __restrict__ P1, const unsigned short* __restrict__ P2,
    const int* __restrict__ offs,
    const float* __restrict__ x, const float* __restrict__ hidden,
    const float* __restrict__ root_xr, const float* __restrict__ root_hr,
    const float* __restrict__ root_xz, const float* __restrict__ root_hz,
    const float* __restrict__ root_xn,
    const float* __restrict__ b_xr, const float* __restrict__ b_hr,
    const float* __restrict__ b_xz, const float* __restrict__ b_hz,
    const float* __restrict__ b_xn,
    float* __restrict__ out)
{
    __shared__ float xsh[4][32];
    __shared__ float hsh[4][64];
    const int w = threadIdx.x >> 6;
    const int o = threadIdx.x & 63;
    const int m = blockIdx.x * 4 + w;
    if (m >= NN_) return;

    if (o < 32) xsh[w][o] = x[(size_t)m * 32 + o];
    const float hval = hidden[(size_t)m * 64 + o];
    hsh[w][o] = hval;

    float axr = 0.f, axz = 0.f, axn = 0.f;
#pragma unroll
    for (int c = 0; c < CH1_; ++c) {
        const unsigned short* p = P1 + ((size_t)c * NN_ + m) * 192;
        axr += bf2f(p[o]); axz += bf2f(p[64 + o]); axn += bf2f(p[128 + o]);
    }
    float ahr = 0.f, ahz = 0.f;
#pragma unroll
    for (int c = 0; c < CH2_; ++c) {
        const unsigned short* p = P2 + ((size_t)c * NN_ + m) * 128;
        ahr += bf2f(p[o]); ahz += bf2f(p[64 + o]);
    }

    const int   dg   = offs[m + 1] - offs[m];
    const float dinv = 1.0f / fmaxf((float)dg, 1.0f);
    axr *= dinv; axz *= dinv; axn *= dinv; ahr *= dinv; ahz *= dinv;

    float sxr = 0.f, sxz = 0.f, sxn = 0.f;
#pragma unroll
    for (int c = 0; c < CIN_; ++c) {
        float xv = xsh[w][c];
        sxr += xv * root_xr[c * 64 + o];
        sxz += xv * root_xz[c * 64 + o];
        sxn += xv * root_xn[c * 64 + o];
    }
    float shr = 0.f, shz = 0.f;
#pragma unroll
    for (int c = 0; c < CHID_; ++c) {
        float hv = hsh[w][c];
        shr += hv * root_hr[c * 64 + o];
        shz += hv * root_hz[c * 64 + o];
    }

    const float conv_xr = axr + sxr + b_xr[o];
    const float conv_xz = axz + sxz + b_xz[o];
    const float conv_xn = axn + sxn + b_xn[o];
    const float hr_out  = ahr + shr + b_hr[o];
    const float conv_hz = ahz + shz + b_hz[o];

    const float rg = 1.0f / (1.0f + expf(-(conv_xr + hr_out)));
    const float zg = 1.0f / (1.0f + expf(-(conv_xz + conv_hz)));
    const float ng = tanhf(conv_xn + rg * hr_out);
    out[(size_t)m * 64 + o] = (1.0f - zg) * ng + zg * hval;
}

// ---------------------------------------------------------------------------
extern "C" void kernel_launch(void* const* d_in, const int* in_sizes, int n_in,
                              void* d_out, int out_size, void* d_ws, size_t ws_size,
                              hipStream_t stream)
{
    const float* x       = (const float*)d_in[0];
    const float* hidden  = (const float*)d_in[1];
    const int*   ei      = (const int*)  d_in[2];
    const float* attr    = (const float*)d_in[3];
    const float* W_xr    = (const float*)d_in[4];
    const float* root_xr = (const float*)d_in[5];
    const float* b_xr    = (const float*)d_in[6];
    const float* W_hr    = (const float*)d_in[7];
    const float* root_hr = (const float*)d_in[8];
    const float* b_hr    = (const float*)d_in[9];
    const float* W_xz    = (const float*)d_in[10];
    const float* root_xz = (const float*)d_in[11];
    const float* b_xz    = (const float*)d_in[12];
    const float* W_hz    = (const float*)d_in[13];
    const float* root_hz = (const float*)d_in[14];
    const float* b_hz    = (const float*)d_in[15];
    const float* W_xn    = (const float*)d_in[16];
    const float* root_xn = (const float*)d_in[17];
    const float* b_xn    = (const float*)d_in[18];
    // d_in[19..21] (W_hn/root_hn/b_hn) are dead: reference reuses hr_out.
    float* out = (float*)d_out;

    // Workspace (~175 MB). No aliasing (gemm-x reads Tx while gemm-h writes
    // P2 concurrently inside gemm_all).
    char* w = (char*)d_ws;
    unsigned short* Tx  = (unsigned short*)w; w += (size_t)NN_ * KK_ * CIN_  * 2;  // 48 MB
    unsigned short* Th  = (unsigned short*)w; w += (size_t)NN_ * KK_ * CHID_ * 2;  // 96 MB
    unsigned short* B1t = (unsigned short*)w; w += (size_t)192 * KK_ * CIN_  * 2;  // 1.5 MB
    unsigned short* B2t = (unsigned short*)w; w += (size_t)128 * KK_ * CHID_ * 2;  // 2.0 MB
    unsigned short* P1  = (unsigned short*)w; w += (size_t)CH1_ * NN_ * 192 * 2;   // 9.2 MB
    unsigned short* P2  = (unsigned short*)w; w += (size_t)CH2_ * NN_ * 128 * 2;   // 12.3 MB
    float4* meta_s = (float4*)w; w += (size_t)EE_ * 16;                            // 3.07 MB
    int* src_s  = (int*)w;   w += (size_t)EE_ * 4;                                 // 0.77 MB
    int* deg    = (int*)w;   w += (size_t)NN_ * 4;
    int* offs   = (int*)w;   w += (size_t)(NN_ + 4) * 4;
    int* cursor = (int*)w;   w += (size_t)NN_ * 4;

    const int MT = (NN_ + 63) / 64;   // 94 m-tiles

    hipMemsetAsync(deg, 0, (size_t)NN_ * 4, stream);

    // ---- launch 1: deg count + weight packs (independent, merged) ----
    const int PACKB = (PK1_ + PK2_ + 255) / 256;
    count_pack_kernel<<<CB_ + PACKB, 256, 0, stream>>>(
        ei, deg, W_xr, W_xz, W_xn, W_hr, W_hz, B1t, B2t);

    // ---- scan + sorted edge records ----
    scan_kernel<<<1, 1024, 0, stream>>>(deg, offs, cursor);
    prep_kernel<<<(EE_ + 255) / 256, 256, 0, stream>>>(ei, attr, cursor, meta_s, src_s);

    // ---- T builds: separate kernels so LDS arena is per-C sized ----
    build_T_kernel<CHID_><<<NN_, 256, 0, stream>>>(meta_s, src_s, hidden, offs, Th);
    build_T_kernel<CIN_><<<NN_, 256, 0, stream>>>(meta_s, src_s, x, offs, Tx);

    // ---- merged x+h GEMMs (co-resident, one launch) ----
    gemm_all_kernel<<<dim3(MT, CH2_ + 2 * CH1_), 256, 0, stream>>>(
        Tx, B1t, P1, Th, B2t, P2);

    // ---- fused reduce + GRU epilogue (wave per node) ----
    epilogue_kernel<<<(NN_ + 3) / 4, 256, 0, stream>>>(
        P1, P2, offs, x, hidden,
        root_xr, root_hr, root_xz, root_hz, root_xn,
        b_xr, b_hr, b_xz, b_hz, b_xn, out);
}

// Round 21
// 286.292 us; speedup vs baseline: 1.0821x; 1.0431x over previous
//
#include <hip/hip_runtime.h>
#include <math.h>

#define NN_   6000
#define EE_   192000
#define CIN_  32
#define CHID_ 64
#define KK_   125   // 5^3 spline kernel cells
#define EB_   32    // edge batch per block in build_T
#define CH1_  4     // x-GEMM outer chunks (each = CPB*64 cols)
#define CH2_  8     // h-GEMM outer chunks
#define CPB_  16    // k-chunks per GEMM block (64 cols each)

// fp32 -> bf16 round-to-nearest-even
static __device__ __forceinline__ unsigned short f2bf(float f) {
    unsigned int u = __builtin_bit_cast(unsigned int, f);
    u += 0x7fff + ((u >> 16) & 1);
    return (unsigned short)(u >> 16);
}
static __device__ __forceinline__ float bf2f(unsigned short h) {
    unsigned int u = ((unsigned int)h) << 16;
    return __builtin_bit_cast(float, u);
}

// ---------------------------------------------------------------------------
// Launch 1: deg count + weight packs (independent work, one launch).
// ---------------------------------------------------------------------------
#define PK1_ (192 * KK_ * CIN_)    // 768000
#define PK2_ (128 * KK_ * CHID_)   // 1024000
#define CB_  ((EE_ + 255) / 256)   // 750 count blocks
__global__ __launch_bounds__(256) void count_pack_kernel(
    const int* __restrict__ ei, int* __restrict__ deg,
    const float* __restrict__ W_xr, const float* __restrict__ W_xz,
    const float* __restrict__ W_xn, const float* __restrict__ W_hr,
    const float* __restrict__ W_hz,
    unsigned short* __restrict__ B1t, unsigned short* __restrict__ B2t)
{
    const int b = blockIdx.x;
    if (b < CB_) {
        int e = b * 256 + threadIdx.x;
        if (e < EE_) atomicAdd(&deg[ei[EE_ + e]], 1);
        return;
    }
    int gid = (b - CB_) * 256 + threadIdx.x;
    if (gid < PK1_) {
        int n  = gid / (KK_ * CIN_);
        int kk = gid % (KK_ * CIN_);
        int conv = n >> 6, o = n & 63;
        const float* W = (conv == 0) ? W_xr : ((conv == 1) ? W_xz : W_xn);
        B1t[gid] = f2bf(W[(size_t)kk * 64 + o]);
    } else if (gid < PK1_ + PK2_) {
        int g2 = gid - PK1_;
        int n  = g2 / (KK_ * CHID_);
        int kk = g2 % (KK_ * CHID_);
        int conv = n >> 6, o = n & 63;
        const float* W = (conv == 0) ? W_hr : W_hz;
        B2t[g2] = f2bf(W[(size_t)kk * 64 + o]);
    }
}

__global__ __launch_bounds__(1024) void scan_kernel(
    const int* __restrict__ deg, int* __restrict__ offs, int* __restrict__ cursor)
{
    __shared__ int part[1024];
    const int tid = threadIdx.x;
    const int CH = (NN_ + 1023) / 1024;   // 6
    const int base = tid * CH;
    int loc[CH];
    int s = 0;
#pragma unroll
    for (int i = 0; i < CH; ++i) {
        int v = (base + i < NN_) ? deg[base + i] : 0;
        loc[i] = s; s += v;
    }
    part[tid] = s;
    __syncthreads();
    for (int off = 1; off < 1024; off <<= 1) {
        int v = (tid >= off) ? part[tid - off] : 0;
        __syncthreads();
        part[tid] += v;
        __syncthreads();
    }
    const int pre = (tid > 0) ? part[tid - 1] : 0;
#pragma unroll
    for (int i = 0; i < CH; ++i) {
        if (base + i < NN_) {
            offs[base + i]   = pre + loc[i];
            cursor[base + i] = pre + loc[i];
        }
    }
    if (tid == 1023) offs[NN_] = part[1023];
}

// Compute per-edge spline meta ONCE, scattered to dst-sorted position.
__global__ __launch_bounds__(256) void prep_kernel(
    const int* __restrict__ ei, const float* __restrict__ attr,
    int* __restrict__ cursor, float4* __restrict__ meta_s, int* __restrict__ src_s)
{
    int e = blockIdx.x * 256 + threadIdx.x;
    if (e >= EE_) return;
    const int dst = ei[EE_ + e];
    const int p   = atomicAdd(&cursor[dst], 1);
    float f[3]; int i0[3];
#pragma unroll
    for (int d = 0; d < 3; ++d) {
        float u  = attr[e * 3 + d] * 4.0f;
        float fl = floorf(u);
        fl = fminf(fmaxf(fl, 0.0f), 3.0f);
        i0[d] = (int)fl;
        f[d]  = u - fl;
    }
    meta_s[p] = make_float4(f[0], f[1], f[2],
        __int_as_float(i0[0] * 25 + i0[1] * 5 + i0[2]));
    src_s[p] = ei[e];
}

// ---------------------------------------------------------------------------
// Per-node T build (R16-proven; separate kernels so LDS is per-C sized:
// x-pass 19.5 KB -> 8 blocks/CU, h-pass 37.9 KB -> 4 blocks/CU).
// Non-atomic b64 LDS RMW; packed-bf16 feat staging.
// ---------------------------------------------------------------------------
template<int C>
__global__ __launch_bounds__(256) void build_T_kernel(
    const float4* __restrict__ meta_s, const int* __restrict__ src_s,
    const float* __restrict__ feat, const int* __restrict__ offs,
    unsigned short* __restrict__ Tb)
{
    constexpr int PAD   = C + 2;
    constexpr int NPAIR = C / 2;
    constexpr int EPI   = (C == 32) ? 2 : 1;     // edges per iteration
    constexpr int PPW   = (C == 32) ? 4 : 8;     // pairs owned per wave
    __shared__ float        Tl[KK_ * PAD];
    __shared__ float4       s_meta[EB_];
    __shared__ int          s_src[EB_];
    __shared__ unsigned int s_fb[EB_ * NPAIR];   // packed bf16 pairs

    const int node = blockIdx.x;
    const int tid  = threadIdx.x;
    const int wave = tid >> 6;
    const int lane = tid & 63;

    for (int i = tid; i < KK_ * PAD; i += 256) Tl[i] = 0.f;

    const int j0 = offs[node], j1 = offs[node + 1];

    const int e2   = (EPI == 2) ? (lane >> 5) : 0;
    const int s_c  = (EPI == 2) ? ((lane >> 2) & 7) : (lane >> 3);
    const int pl   = (EPI == 2) ? (lane & 3) : (lane & 7);
    const int pidx = wave * PPW + pl;
    const int cb0 = s_c & 1, cb1 = (s_c >> 1) & 1, cb2 = (s_c >> 2) & 1;
    const int offc = cb0 * 25 + cb1 * 5 + cb2;

    __syncthreads();

    for (int jb = j0; jb < j1; jb += EB_) {
        const int m = min(EB_, j1 - jb);

        if (tid < m) {
            s_meta[tid] = meta_s[jb + tid];
            s_src[tid]  = src_s[jb + tid];
        }
        __syncthreads();

        for (int u = tid; u < m * NPAIR; u += 256) {
            const int r = u / NPAIR, q = u % NPAIR;
            float2 v = *(const float2*)&feat[(size_t)s_src[r] * C + 2 * q];
            s_fb[u] = (unsigned int)f2bf(v.x) | ((unsigned int)f2bf(v.y) << 16);
        }
        __syncthreads();

        for (int eb = 0; eb < m; eb += EPI) {
            const int e = eb + e2;
            if (EPI == 1 || e < m) {
                const float4 mt = s_meta[e];
                const int base  = __float_as_int(mt.w);
                const float p = (cb0 ? mt.x : 1.f - mt.x) *
                                (cb1 ? mt.y : 1.f - mt.y) *
                                (cb2 ? mt.z : 1.f - mt.z);
                const unsigned int fp = s_fb[e * NPAIR + pidx];
                const float fx = bf2f((unsigned short)(fp & 0xffff));
                const float fy = bf2f((unsigned short)(fp >> 16));
                float* cell = &Tl[(base + offc) * PAD + 2 * pidx];
                cell[0] += p * fx;
                cell[1] += p * fy;
            }
        }
        __syncthreads();
    }

    unsigned int* To = (unsigned int*)(Tb + (size_t)node * (KK_ * C));
    for (int u = tid; u < KK_ * NPAIR; u += 256) {
        int k = u / NPAIR, pp = u % NPAIR;
        unsigned int lo = f2bf(Tl[k * PAD + 2 * pp]);
        unsigned int hi = f2bf(Tl[k * PAD + 2 * pp + 1]);
        To[u] = lo | (hi << 16);
    }
}

// ---------------------------------------------------------------------------
// GEMM body v7: COLS=64 (was 128), CPB=16. LDS h: 34.8->18.4 KB, x: 26->13.8
// -> resident capacity 4 -> ~7 blocks/CU (grid-capped ~5.9). Continues the
// R14->R15 occupancy curve (COLS 256->128 bought 76->61 us at identical
// structure). Barrier-free inner loop, A-frags per-lane direct from global,
// no cross-chunk prefetch (R19 lesson: compiler vmcnt defeats it).
// ---------------------------------------------------------------------------
template<int NT, int NTF, int CPB>
static __device__ __forceinline__ void gemm_body(
    unsigned char* arena,
    const unsigned short* __restrict__ A, const unsigned short* __restrict__ Bt,
    unsigned short* __restrict__ P, int M, int Kd, int chunk, int zhalf)
{
    constexpr int SPC   = 2;
    constexpr int COLS  = SPC * 32;       // 64
    constexpr int BP    = COLS + 8;       // 72 shorts (16B-aligned pitch,
                                          // l16 stride-4 banks -> 2-way free)
    constexpr int NFRAG = NT / 16;
    constexpr int CSP   = NT + 8;
    unsigned short (*Bs)[BP] = (unsigned short(*)[BP])arena;

    using bf16x8 = __attribute__((ext_vector_type(8))) short;
    using f32x4  = __attribute__((ext_vector_type(4))) float;

    const int tid  = threadIdx.x;
    const int wave = tid >> 6;
    const int lane = tid & 63;
    const int quad = lane >> 4;
    const int l16  = lane & 15;
    const int m0   = blockIdx.x * 64;
    const unsigned short* Bp = Bt + (size_t)zhalf * NT * Kd;

    const int  arow   = m0 + wave * 16 + l16;
    const bool avalid = arow < M;
    const unsigned short* Ap = A + (size_t)(avalid ? arow : 0) * Kd;

    f32x4 acc[NFRAG];
#pragma unroll
    for (int f = 0; f < NFRAG; ++f) acc[f] = (f32x4){0.f, 0.f, 0.f, 0.f};

    for (int cc = 0; cc < CPB; ++cc) {
        const int k0 = (chunk * CPB + cc) * COLS;
        if (k0 >= Kd) break;
        const int ksz = min(Kd - k0, COLS);

        __syncthreads();

        constexpr int BUNITS = NT * COLS / 8;
        for (int u = tid; u < BUNITS; u += 256) {
            const int row = u / (COLS / 8);
            const int cq  = (u % (COLS / 8)) * 8;
            uint4 v = make_uint4(0u, 0u, 0u, 0u);
            if (cq < ksz) v = *(const uint4*)(Bp + (size_t)row * Kd + k0 + cq);
            *(uint4*)&Bs[row][cq] = v;
        }

        uint4 afr[SPC];
#pragma unroll
        for (int s = 0; s < SPC; ++s) {
            const int k = k0 + s * 32 + quad * 8;
            afr[s] = (avalid && k < Kd) ? *(const uint4*)(Ap + k)
                                        : make_uint4(0u, 0u, 0u, 0u);
        }

        __syncthreads();

#pragma unroll
        for (int s = 0; s < SPC; ++s) {
            bf16x8 af = __builtin_bit_cast(bf16x8, afr[s]);
#pragma unroll
            for (int f = 0; f < NFRAG; ++f) {
                bf16x8 bfv = *(bf16x8*)&Bs[f * 16 + l16][s * 32 + quad * 8];
                acc[f] = __builtin_amdgcn_mfma_f32_16x16x32_bf16(af, bfv, acc[f], 0, 0, 0);
            }
        }
    }

    __syncthreads();
    unsigned short* Cs = (unsigned short*)arena;   // [64][CSP]
    const int rbase = wave * 16 + quad * 4;
#pragma unroll
    for (int f = 0; f < NFRAG; ++f) {
        const int col = f * 16 + l16;
#pragma unroll
        for (int r = 0; r < 4; ++r)
            Cs[(rbase + r) * CSP + col] = f2bf(acc[f][r]);
    }
    __syncthreads();
    unsigned short* Pc = P + ((size_t)chunk * M + m0) * NTF + zhalf * NT;
    constexpr int UNITS = 64 * NT / 8;
    for (int u = tid; u < UNITS; u += 256) {
        const int row = (u * 8) / NT, col = (u * 8) % NT;
        if (m0 + row < M)
            *(uint4*)&Pc[(size_t)row * NTF + col] = *(const uint4*)&Cs[row * CSP + col];
    }
}

// Merged GEMM: blockIdx.y < CH2_ -> h-chunk; else x-(chunk,half).
// Arena = max(Bs_h=128*72*2=18432, Cs_h=64*136*2=17408) = 18432 B.
__global__ __launch_bounds__(256) void gemm_all_kernel(
    const unsigned short* __restrict__ Tx, const unsigned short* __restrict__ B1t,
    unsigned short* __restrict__ P1,
    const unsigned short* __restrict__ Th, const unsigned short* __restrict__ B2t,
    unsigned short* __restrict__ P2)
{
    __shared__ __align__(16) unsigned char arena[128 * 72 * 2];
    const int y = blockIdx.y;
    if (y < CH2_) {
        gemm_body<128, 128, CPB_>(arena, Th, B2t, P2, NN_, KK_ * CHID_, y, 0);
    } else {
        const int g = y - CH2_;            // 0..7 -> (chunk 0..3, half 0..1)
        gemm_body<96, 192, CPB_>(arena, Tx, B1t, P1, NN_, KK_ * CIN_, g >> 1, g & 1);
    }
}

// ---------------------------------------------------------------------------
// Epilogue: one wave per node, lane = output channel. Sums bf16 split-K
// partials (L2-resident), mean-agg, root GEMV, GRU gates.
// ---------------------------------------------------------------------------
__global__ __launch_bounds__(256) void epilogue_kernel(
    const unsigned short* __restrict__ P1, const unsigned short* __restrict__ P2,
    const int* __restrict__ offs,
    const float* __restrict__ x, const float* __restrict__ hidden,
    const float* __restrict__ root_xr, const float* __restrict__ root_hr,
    const float* __restrict__ root_xz, const float* __restrict__ root_hz,
    const float* __restrict__ root_xn,
    const float* __restrict__ b_xr, const float* __restrict__ b_hr,
    const float* __restrict__ b_xz, const float* __restrict__ b_hz,
    const float* __restrict__ b_xn,
    float* __restrict__ out)
{
    __shared__ float xsh[4][32];
    __shared__ float hsh[4][64];
    const int w = threadIdx.x >> 6;
    const int o = threadIdx.x & 63;
    const int m = blockIdx.x * 4 + w;
    if (m >= NN_) return;

    if (o < 32) xsh[w][o] = x[(size_t)m * 32 + o];
    const float hval = hidden[(size_t)m * 64 + o];
    hsh[w][o] = hval;

    float axr = 0.f, axz = 0.f, axn = 0.f;
#pragma unroll
    for (int c = 0; c < CH1_; ++c) {
        const unsigned short* p = P1 + ((size_t)c * NN_ + m) * 192;
        axr += bf2f(p[o]); axz += bf2f(p[64 + o]); axn += bf2f(p[128 + o]);
    }
    float ahr = 0.f, ahz = 0.f;
#pragma unroll
    for (int c = 0; c < CH2_; ++c) {
        const unsigned short* p = P2 + ((size_t)c * NN_ + m) * 128;
        ahr += bf2f(p[o]); ahz += bf2f(p[64 + o]);
    }

    const int   dg   = offs[m + 1] - offs[m];
    const float dinv = 1.0f / fmaxf((float)dg, 1.0f);
    axr *= dinv; axz *= dinv; axn *= dinv; ahr *= dinv; ahz *= dinv;

    float sxr = 0.f, sxz = 0.f, sxn = 0.f;
#pragma unroll
    for (int c = 0; c < CIN_; ++c) {
        float xv = xsh[w][c];
        sxr += xv * root_xr[c * 64 + o];
        sxz += xv * root_xz[c * 64 + o];
        sxn += xv * root_xn[c * 64 + o];
    }
    float shr = 0.f, shz = 0.f;
#pragma unroll
    for (int c = 0; c < CHID_; ++c) {
        float hv = hsh[w][c];
        shr += hv * root_hr[c * 64 + o];
        shz += hv * root_hz[c * 64 + o];
    }

    const float conv_xr = axr + sxr + b_xr[o];
    const float conv_xz = axz + sxz + b_xz[o];
    const float conv_xn = axn + sxn + b_xn[o];
    const float hr_out  = ahr + shr + b_hr[o];
    const float conv_hz = ahz + shz + b_hz[o];

    const float rg = 1.0f / (1.0f + expf(-(conv_xr + hr_out)));
    const float zg = 1.0f / (1.0f + expf(-(conv_xz + conv_hz)));
    const float ng = tanhf(conv_xn + rg * hr_out);
    out[(size_t)m * 64 + o] = (1.0f - zg) * ng + zg * hval;
}

// ---------------------------------------------------------------------------
extern "C" void kernel_launch(void* const* d_in, const int* in_sizes, int n_in,
                              void* d_out, int out_size, void* d_ws, size_t ws_size,
                              hipStream_t stream)
{
    const float* x       = (const float*)d_in[0];
    const float* hidden  = (const float*)d_in[1];
    const int*   ei      = (const int*)  d_in[2];
    const float* attr    = (const float*)d_in[3];
    const float* W_xr    = (const float*)d_in[4];
    const float* root_xr = (const float*)d_in[5];
    const float* b_xr    = (const float*)d_in[6];
    const float* W_hr    = (const float*)d_in[7];
    const float* root_hr = (const float*)d_in[8];
    const float* b_hr    = (const float*)d_in[9];
    const float* W_xz    = (const float*)d_in[10];
    const float* root_xz = (const float*)d_in[11];
    const float* b_xz    = (const float*)d_in[12];
    const float* W_hz    = (const float*)d_in[13];
    const float* root_hz = (const float*)d_in[14];
    const float* b_hz    = (const float*)d_in[15];
    const float* W_xn    = (const float*)d_in[16];
    const float* root_xn = (const float*)d_in[17];
    const float* b_xn    = (const float*)d_in[18];
    // d_in[19..21] (W_hn/root_hn/b_hn) are dead: reference reuses hr_out.
    float* out = (float*)d_out;

    // Workspace (~175 MB). No aliasing (gemm-x reads Tx while gemm-h writes
    // P2 concurrently inside gemm_all).
    char* w = (char*)d_ws;
    unsigned short* Tx  = (unsigned short*)w; w += (size_t)NN_ * KK_ * CIN_  * 2;  // 48 MB
    unsigned short* Th  = (unsigned short*)w; w += (size_t)NN_ * KK_ * CHID_ * 2;  // 96 MB
    unsigned short* B1t = (unsigned short*)w; w += (size_t)192 * KK_ * CIN_  * 2;  // 1.5 MB
    unsigned short* B2t = (unsigned short*)w; w += (size_t)128 * KK_ * CHID_ * 2;  // 2.0 MB
    unsigned short* P1  = (unsigned short*)w; w += (size_t)CH1_ * NN_ * 192 * 2;   // 9.2 MB
    unsigned short* P2  = (unsigned short*)w; w += (size_t)CH2_ * NN_ * 128 * 2;   // 12.3 MB
    float4* meta_s = (float4*)w; w += (size_t)EE_ * 16;                            // 3.07 MB
    int* src_s  = (int*)w;   w += (size_t)EE_ * 4;                                 // 0.77 MB
    int* deg    = (int*)w;   w += (size_t)NN_ * 4;
    int* offs   = (int*)w;   w += (size_t)(NN_ + 4) * 4;
    int* cursor = (int*)w;   w += (size_t)NN_ * 4;

    const int MT = (NN_ + 63) / 64;   // 94 m-tiles

    hipMemsetAsync(deg, 0, (size_t)NN_ * 4, stream);

    // ---- launch 1: deg count + weight packs (independent, merged) ----
    const int PACKB = (PK1_ + PK2_ + 255) / 256;
    count_pack_kernel<<<CB_ + PACKB, 256, 0, stream>>>(
        ei, deg, W_xr, W_xz, W_xn, W_hr, W_hz, B1t, B2t);

    // ---- scan + sorted edge records ----
    scan_kernel<<<1, 1024, 0, stream>>>(deg, offs, cursor);
    prep_kernel<<<(EE_ + 255) / 256, 256, 0, stream>>>(ei, attr, cursor, meta_s, src_s);

    // ---- T builds: separate kernels so LDS arena is per-C sized ----
    build_T_kernel<CHID_><<<NN_, 256, 0, stream>>>(meta_s, src_s, hidden, offs, Th);
    build_T_kernel<CIN_><<<NN_, 256, 0, stream>>>(meta_s, src_s, x, offs, Tx);

    // ---- merged x+h GEMMs (co-resident, one launch) ----
    gemm_all_kernel<<<dim3(MT, CH2_ + 2 * CH1_), 256, 0, stream>>>(
        Tx, B1t, P1, Th, B2t, P2);

    // ---- fused reduce + GRU epilogue (wave per node) ----
    epilogue_kernel<<<(NN_ + 3) / 4, 256, 0, stream>>>(
        P1, P2, offs, x, hidden,
        root_xr, root_hr, root_xz, root_hz, root_xn,
        b_xr, b_hr, b_xz, b_hz, b_xn, out);
}

// Round 22
// 284.702 us; speedup vs baseline: 1.0882x; 1.0056x over previous
//
#include <hip/hip_runtime.h>
#include <math.h>

#define NN_   6000
#define EE_   192000
#define CIN_  32
#define CHID_ 64
#define KK_   125   // 5^3 spline kernel cells
#define EB_   32    // edge batch per block in build_T
#define CH1_  4     // x-GEMM outer chunks (each = CPB*64 cols)
#define CH2_  8     // h-GEMM outer chunks
#define CPB_  16    // k-chunks per GEMM block (64 cols each)

// fp32 -> bf16 round-to-nearest-even
static __device__ __forceinline__ unsigned short f2bf(float f) {
    unsigned int u = __builtin_bit_cast(unsigned int, f);
    u += 0x7fff + ((u >> 16) & 1);
    return (unsigned short)(u >> 16);
}
static __device__ __forceinline__ float bf2f(unsigned short h) {
    unsigned int u = ((unsigned int)h) << 16;
    return __builtin_bit_cast(float, u);
}

// ---------------------------------------------------------------------------
// Launch 1: deg count + weight packs (independent work, one launch).
// ---------------------------------------------------------------------------
#define PK1_ (192 * KK_ * CIN_)    // 768000
#define PK2_ (128 * KK_ * CHID_)   // 1024000
#define CB_  ((EE_ + 255) / 256)   // 750 count blocks
__global__ __launch_bounds__(256) void count_pack_kernel(
    const int* __restrict__ ei, int* __restrict__ deg,
    const float* __restrict__ W_xr, const float* __restrict__ W_xz,
    const float* __restrict__ W_xn, const float* __restrict__ W_hr,
    const float* __restrict__ W_hz,
    unsigned short* __restrict__ B1t, unsigned short* __restrict__ B2t)
{
    const int b = blockIdx.x;
    if (b < CB_) {
        int e = b * 256 + threadIdx.x;
        if (e < EE_) atomicAdd(&deg[ei[EE_ + e]], 1);
        return;
    }
    int gid = (b - CB_) * 256 + threadIdx.x;
    if (gid < PK1_) {
        int n  = gid / (KK_ * CIN_);
        int kk = gid % (KK_ * CIN_);
        int conv = n >> 6, o = n & 63;
        const float* W = (conv == 0) ? W_xr : ((conv == 1) ? W_xz : W_xn);
        B1t[gid] = f2bf(W[(size_t)kk * 64 + o]);
    } else if (gid < PK1_ + PK2_) {
        int g2 = gid - PK1_;
        int n  = g2 / (KK_ * CHID_);
        int kk = g2 % (KK_ * CHID_);
        int conv = n >> 6, o = n & 63;
        const float* W = (conv == 0) ? W_hr : W_hz;
        B2t[g2] = f2bf(W[(size_t)kk * 64 + o]);
    }
}

__global__ __launch_bounds__(1024) void scan_kernel(
    const int* __restrict__ deg, int* __restrict__ offs, int* __restrict__ cursor)
{
    __shared__ int part[1024];
    const int tid = threadIdx.x;
    const int CH = (NN_ + 1023) / 1024;   // 6
    const int base = tid * CH;
    int loc[CH];
    int s = 0;
#pragma unroll
    for (int i = 0; i < CH; ++i) {
        int v = (base + i < NN_) ? deg[base + i] : 0;
        loc[i] = s; s += v;
    }
    part[tid] = s;
    __syncthreads();
    for (int off = 1; off < 1024; off <<= 1) {
        int v = (tid >= off) ? part[tid - off] : 0;
        __syncthreads();
        part[tid] += v;
        __syncthreads();
    }
    const int pre = (tid > 0) ? part[tid - 1] : 0;
#pragma unroll
    for (int i = 0; i < CH; ++i) {
        if (base + i < NN_) {
            offs[base + i]   = pre + loc[i];
            cursor[base + i] = pre + loc[i];
        }
    }
    if (tid == 1023) offs[NN_] = part[1023];
}

// Compute per-edge spline meta ONCE, scattered to dst-sorted position.
__global__ __launch_bounds__(256) void prep_kernel(
    const int* __restrict__ ei, const float* __restrict__ attr,
    int* __restrict__ cursor, float4* __restrict__ meta_s, int* __restrict__ src_s)
{
    int e = blockIdx.x * 256 + threadIdx.x;
    if (e >= EE_) return;
    const int dst = ei[EE_ + e];
    const int p   = atomicAdd(&cursor[dst], 1);
    float f[3]; int i0[3];
#pragma unroll
    for (int d = 0; d < 3; ++d) {
        float u  = attr[e * 3 + d] * 4.0f;
        float fl = floorf(u);
        fl = fminf(fmaxf(fl, 0.0f), 3.0f);
        i0[d] = (int)fl;
        f[d]  = u - fl;
    }
    meta_s[p] = make_float4(f[0], f[1], f[2],
        __int_as_float(i0[0] * 25 + i0[1] * 5 + i0[2]));
    src_s[p] = ei[e];
}

// ---------------------------------------------------------------------------
// Per-node T build v3: phase 1 now PRECOMPUTES the 8 basis products per edge
// (two float4 LDS stores) so phase 3 reads p = s_basis[e*8+s_c] (8-lane
// broadcast) instead of recomputing 5 VALU ops per edge per lane -- phase 3
// was 55% VALUBusy in R21. Non-atomic b64 LDS RMW; packed-bf16 feat staging.
// ---------------------------------------------------------------------------
template<int C>
__global__ __launch_bounds__(256) void build_T_kernel(
    const float4* __restrict__ meta_s, const int* __restrict__ src_s,
    const float* __restrict__ feat, const int* __restrict__ offs,
    unsigned short* __restrict__ Tb)
{
    constexpr int PAD   = C + 2;
    constexpr int NPAIR = C / 2;
    constexpr int EPI   = (C == 32) ? 2 : 1;     // edges per iteration
    constexpr int PPW   = (C == 32) ? 4 : 8;     // pairs owned per wave
    __shared__ float        Tl[KK_ * PAD];
    __shared__ int          s_base[EB_];
    __shared__ float        s_basis[EB_ * 8];
    __shared__ int          s_src[EB_];
    __shared__ unsigned int s_fb[EB_ * NPAIR];   // packed bf16 pairs

    const int node = blockIdx.x;
    const int tid  = threadIdx.x;
    const int wave = tid >> 6;
    const int lane = tid & 63;

    for (int i = tid; i < KK_ * PAD; i += 256) Tl[i] = 0.f;

    const int j0 = offs[node], j1 = offs[node + 1];

    const int e2   = (EPI == 2) ? (lane >> 5) : 0;
    const int s_c  = (EPI == 2) ? ((lane >> 2) & 7) : (lane >> 3);
    const int pl   = (EPI == 2) ? (lane & 3) : (lane & 7);
    const int pidx = wave * PPW + pl;
    const int cb0 = s_c & 1, cb1 = (s_c >> 1) & 1, cb2 = (s_c >> 2) & 1;
    const int offc = cb0 * 25 + cb1 * 5 + cb2;

    __syncthreads();

    for (int jb = j0; jb < j1; jb += EB_) {
        const int m = min(EB_, j1 - jb);

        // phase 1: load edge records; precompute base + all 8 basis products
        if (tid < m) {
            const float4 mt = meta_s[jb + tid];
            s_src[tid]  = src_s[jb + tid];
            s_base[tid] = __float_as_int(mt.w);
            const float f0 = mt.x, f1 = mt.y, f2 = mt.z;
            const float g0 = 1.f - f0, g1 = 1.f - f1, g2 = 1.f - f2;
            float4 blo = make_float4(g0 * g1 * g2, f0 * g1 * g2,
                                     g0 * f1 * g2, f0 * f1 * g2);
            float4 bhi = make_float4(g0 * g1 * f2, f0 * g1 * f2,
                                     g0 * f1 * f2, f0 * f1 * f2);
            *(float4*)&s_basis[tid * 8]     = blo;
            *(float4*)&s_basis[tid * 8 + 4] = bhi;
        }
        __syncthreads();

        // phase 2: gather feature rows -> packed bf16 in LDS
        for (int u = tid; u < m * NPAIR; u += 256) {
            const int r = u / NPAIR, q = u % NPAIR;
            float2 v = *(const float2*)&feat[(size_t)s_src[r] * C + 2 * q];
            s_fb[u] = (unsigned int)f2bf(v.x) | ((unsigned int)f2bf(v.y) << 16);
        }
        __syncthreads();

        // phase 3: race-free LDS accumulate (basis/base read, not recomputed)
        for (int eb = 0; eb < m; eb += EPI) {
            const int e = eb + e2;
            if (EPI == 1 || e < m) {
                const int   base = s_base[e];
                const float p    = s_basis[e * 8 + s_c];
                const unsigned int fp = s_fb[e * NPAIR + pidx];
                const float fx = bf2f((unsigned short)(fp & 0xffff));
                const float fy = bf2f((unsigned short)(fp >> 16));
                float* cell = &Tl[(base + offc) * PAD + 2 * pidx];
                cell[0] += p * fx;
                cell[1] += p * fy;
            }
        }
        __syncthreads();
    }

    unsigned int* To = (unsigned int*)(Tb + (size_t)node * (KK_ * C));
    for (int u = tid; u < KK_ * NPAIR; u += 256) {
        int k = u / NPAIR, pp = u % NPAIR;
        unsigned int lo = f2bf(Tl[k * PAD + 2 * pp]);
        unsigned int hi = f2bf(Tl[k * PAD + 2 * pp + 1]);
        To[u] = lo | (hi << 16);
    }
}

// ---------------------------------------------------------------------------
// GEMM body v7 (R21-proven): COLS=64, CPB=16, barrier-free inner loop,
// A-frags per-lane direct from global, no cross-chunk prefetch (R19 lesson).
// ---------------------------------------------------------------------------
template<int NT, int NTF, int CPB>
static __device__ __forceinline__ void gemm_body(
    unsigned char* arena,
    const unsigned short* __restrict__ A, const unsigned short* __restrict__ Bt,
    unsigned short* __restrict__ P, int M, int Kd, int chunk, int zhalf)
{
    constexpr int SPC   = 2;
    constexpr int COLS  = SPC * 32;       // 64
    constexpr int BP    = COLS + 8;       // 72 shorts
    constexpr int NFRAG = NT / 16;
    constexpr int CSP   = NT + 8;
    unsigned short (*Bs)[BP] = (unsigned short(*)[BP])arena;

    using bf16x8 = __attribute__((ext_vector_type(8))) short;
    using f32x4  = __attribute__((ext_vector_type(4))) float;

    const int tid  = threadIdx.x;
    const int wave = tid >> 6;
    const int lane = tid & 63;
    const int quad = lane >> 4;
    const int l16  = lane & 15;
    const int m0   = blockIdx.x * 64;
    const unsigned short* Bp = Bt + (size_t)zhalf * NT * Kd;

    const int  arow   = m0 + wave * 16 + l16;
    const bool avalid = arow < M;
    const unsigned short* Ap = A + (size_t)(avalid ? arow : 0) * Kd;

    f32x4 acc[NFRAG];
#pragma unroll
    for (int f = 0; f < NFRAG; ++f) acc[f] = (f32x4){0.f, 0.f, 0.f, 0.f};

    for (int cc = 0; cc < CPB; ++cc) {
        const int k0 = (chunk * CPB + cc) * COLS;
        if (k0 >= Kd) break;
        const int ksz = min(Kd - k0, COLS);

        __syncthreads();

        constexpr int BUNITS = NT * COLS / 8;
        for (int u = tid; u < BUNITS; u += 256) {
            const int row = u / (COLS / 8);
            const int cq  = (u % (COLS / 8)) * 8;
            uint4 v = make_uint4(0u, 0u, 0u, 0u);
            if (cq < ksz) v = *(const uint4*)(Bp + (size_t)row * Kd + k0 + cq);
            *(uint4*)&Bs[row][cq] = v;
        }

        uint4 afr[SPC];
#pragma unroll
        for (int s = 0; s < SPC; ++s) {
            const int k = k0 + s * 32 + quad * 8;
            afr[s] = (avalid && k < Kd) ? *(const uint4*)(Ap + k)
                                        : make_uint4(0u, 0u, 0u, 0u);
        }

        __syncthreads();

#pragma unroll
        for (int s = 0; s < SPC; ++s) {
            bf16x8 af = __builtin_bit_cast(bf16x8, afr[s]);
#pragma unroll
            for (int f = 0; f < NFRAG; ++f) {
                bf16x8 bfv = *(bf16x8*)&Bs[f * 16 + l16][s * 32 + quad * 8];
                acc[f] = __builtin_amdgcn_mfma_f32_16x16x32_bf16(af, bfv, acc[f], 0, 0, 0);
            }
        }
    }

    __syncthreads();
    unsigned short* Cs = (unsigned short*)arena;   // [64][CSP]
    const int rbase = wave * 16 + quad * 4;
#pragma unroll
    for (int f = 0; f < NFRAG; ++f) {
        const int col = f * 16 + l16;
#pragma unroll
        for (int r = 0; r < 4; ++r)
            Cs[(rbase + r) * CSP + col] = f2bf(acc[f][r]);
    }
    __syncthreads();
    unsigned short* Pc = P + ((size_t)chunk * M + m0) * NTF + zhalf * NT;
    constexpr int UNITS = 64 * NT / 8;
    for (int u = tid; u < UNITS; u += 256) {
        const int row = (u * 8) / NT, col = (u * 8) % NT;
        if (m0 + row < M)
            *(uint4*)&Pc[(size_t)row * NTF + col] = *(const uint4*)&Cs[row * CSP + col];
    }
}

// Merged GEMM: blockIdx.y < CH2_ -> h-chunk; else x-(chunk,half).
__global__ __launch_bounds__(256) void gemm_all_kernel(
    const unsigned short* __restrict__ Tx, const unsigned short* __restrict__ B1t,
    unsigned short* __restrict__ P1,
    const unsigned short* __restrict__ Th, const unsigned short* __restrict__ B2t,
    unsigned short* __restrict__ P2)
{
    __shared__ __align__(16) unsigned char arena[128 * 72 * 2];
    const int y = blockIdx.y;
    if (y < CH2_) {
        gemm_body<128, 128, CPB_>(arena, Th, B2t, P2, NN_, KK_ * CHID_, y, 0);
    } else {
        const int g = y - CH2_;            // 0..7 -> (chunk 0..3, half 0..1)
        gemm_body<96, 192, CPB_>(arena, Tx, B1t, P1, NN_, KK_ * CIN_, g >> 1, g & 1);
    }
}

// ---------------------------------------------------------------------------
// Epilogue: one wave per node, lane = output channel. Sums bf16 split-K
// partials (L2-resident), mean-agg, root GEMV, GRU gates.
// ---------------------------------------------------------------------------
__global__ __launch_bounds__(256) void epilogue_kernel(
    const unsigned short* __restrict__ P1, const unsigned short* __restrict__ P2,
    const int* __restrict__ offs,
    const float* __restrict__ x, const float* __restrict__ hidden,
    const float* __restrict__ root_xr, const float* __restrict__ root_hr,
    const float* __restrict__ root_xz, const float* __restrict__ root_hz,
    const float* __restrict__ root_xn,
    const float* __restrict__ b_xr, const float* __restrict__ b_hr,
    const float* __restrict__ b_xz, const float* __restrict__ b_hz,
    const float* __restrict__ b_xn,
    float* __restrict__ out)
{
    __shared__ float xsh[4][32];
    __shared__ float hsh[4][64];
    const int w = threadIdx.x >> 6;
    const int o = threadIdx.x & 63;
    const int m = blockIdx.x * 4 + w;
    if (m >= NN_) return;

    if (o < 32) xsh[w][o] = x[(size_t)m * 32 + o];
    const float hval = hidden[(size_t)m * 64 + o];
    hsh[w][o] = hval;

    float axr = 0.f, axz = 0.f, axn = 0.f;
#pragma unroll
    for (int c = 0; c < CH1_; ++c) {
        const unsigned short* p = P1 + ((size_t)c * NN_ + m) * 192;
        axr += bf2f(p[o]); axz += bf2f(p[64 + o]); axn += bf2f(p[128 + o]);
    }
    float ahr = 0.f, ahz = 0.f;
#pragma unroll
    for (int c = 0; c < CH2_; ++c) {
        const unsigned short* p = P2 + ((size_t)c * NN_ + m) * 128;
        ahr += bf2f(p[o]); ahz += bf2f(p[64 + o]);
    }

    const int   dg   = offs[m + 1] - offs[m];
    const float dinv = 1.0f / fmaxf((float)dg, 1.0f);
    axr *= dinv; axz *= dinv; axn *= dinv; ahr *= dinv; ahz *= dinv;

    float sxr = 0.f, sxz = 0.f, sxn = 0.f;
#pragma unroll
    for (int c = 0; c < CIN_; ++c) {
        float xv = xsh[w][c];
        sxr += xv * root_xr[c * 64 + o];
        sxz += xv * root_xz[c * 64 + o];
        sxn += xv * root_xn[c * 64 + o];
    }
    float shr = 0.f, shz = 0.f;
#pragma unroll
    for (int c = 0; c < CHID_; ++c) {
        float hv = hsh[w][c];
        shr += hv * root_hr[c * 64 + o];
        shz += hv * root_hz[c * 64 + o];
    }

    const float conv_xr = axr + sxr + b_xr[o];
    const float conv_xz = axz + sxz + b_xz[o];
    const float conv_xn = axn + sxn + b_xn[o];
    const float hr_out  = ahr + shr + b_hr[o];
    const float conv_hz = ahz + shz + b_hz[o];

    const float rg = 1.0f / (1.0f + expf(-(conv_xr + hr_out)));
    const float zg = 1.0f / (1.0f + expf(-(conv_xz + conv_hz)));
    const float ng = tanhf(conv_xn + rg * hr_out);
    out[(size_t)m * 64 + o] = (1.0f - zg) * ng + zg * hval;
}

// ---------------------------------------------------------------------------
extern "C" void kernel_launch(void* const* d_in, const int* in_sizes, int n_in,
                              void* d_out, int out_size, void* d_ws, size_t ws_size,
                              hipStream_t stream)
{
    const float* x       = (const float*)d_in[0];
    const float* hidden  = (const float*)d_in[1];
    const int*   ei      = (const int*)  d_in[2];
    const float* attr    = (const float*)d_in[3];
    const float* W_xr    = (const float*)d_in[4];
    const float* root_xr = (const float*)d_in[5];
    const float* b_xr    = (const float*)d_in[6];
    const float* W_hr    = (const float*)d_in[7];
    const float* root_hr = (const float*)d_in[8];
    const float* b_hr    = (const float*)d_in[9];
    const float* W_xz    = (const float*)d_in[10];
    const float* root_xz = (const float*)d_in[11];
    const float* b_xz    = (const float*)d_in[12];
    const float* W_hz    = (const float*)d_in[13];
    const float* root_hz = (const float*)d_in[14];
    const float* b_hz    = (const float*)d_in[15];
    const float* W_xn    = (const float*)d_in[16];
    const float* root_xn = (const float*)d_in[17];
    const float* b_xn    = (const float*)d_in[18];
    // d_in[19..21] (W_hn/root_hn/b_hn) are dead: reference reuses hr_out.
    float* out = (float*)d_out;

    // Workspace (~175 MB). No aliasing (gemm-x reads Tx while gemm-h writes
    // P2 concurrently inside gemm_all).
    char* w = (char*)d_ws;
    unsigned short* Tx  = (unsigned short*)w; w += (size_t)NN_ * KK_ * CIN_  * 2;  // 48 MB
    unsigned short* Th  = (unsigned short*)w; w += (size_t)NN_ * KK_ * CHID_ * 2;  // 96 MB
    unsigned short* B1t = (unsigned short*)w; w += (size_t)192 * KK_ * CIN_  * 2;  // 1.5 MB
    unsigned short* B2t = (unsigned short*)w; w += (size_t)128 * KK_ * CHID_ * 2;  // 2.0 MB
    unsigned short* P1  = (unsigned short*)w; w += (size_t)CH1_ * NN_ * 192 * 2;   // 9.2 MB
    unsigned short* P2  = (unsigned short*)w; w += (size_t)CH2_ * NN_ * 128 * 2;   // 12.3 MB
    float4* meta_s = (float4*)w; w += (size_t)EE_ * 16;                            // 3.07 MB
    int* src_s  = (int*)w;   w += (size_t)EE_ * 4;                                 // 0.77 MB
    int* deg    = (int*)w;   w += (size_t)NN_ * 4;
    int* offs   = (int*)w;   w += (size_t)(NN_ + 4) * 4;
    int* cursor = (int*)w;   w += (size_t)NN_ * 4;

    const int MT = (NN_ + 63) / 64;   // 94 m-tiles

    hipMemsetAsync(deg, 0, (size_t)NN_ * 4, stream);

    // ---- launch 1: deg count + weight packs (independent, merged) ----
    const int PACKB = (PK1_ + PK2_ + 255) / 256;
    count_pack_kernel<<<CB_ + PACKB, 256, 0, stream>>>(
        ei, deg, W_xr, W_xz, W_xn, W_hr, W_hz, B1t, B2t);

    // ---- scan + sorted edge records ----
    scan_kernel<<<1, 1024, 0, stream>>>(deg, offs, cursor);
    prep_kernel<<<(EE_ + 255) / 256, 256, 0, stream>>>(ei, attr, cursor, meta_s, src_s);

    // ---- T builds: separate kernels so LDS arena is per-C sized ----
    build_T_kernel<CHID_><<<NN_, 256, 0, stream>>>(meta_s, src_s, hidden, offs, Th);
    build_T_kernel<CIN_><<<NN_, 256, 0, stream>>>(meta_s, src_s, x, offs, Tx);

    // ---- merged x+h GEMMs (co-resident, one launch) ----
    gemm_all_kernel<<<dim3(MT, CH2_ + 2 * CH1_), 256, 0, stream>>>(
        Tx, B1t, P1, Th, B2t, P2);

    // ---- fused reduce + GRU epilogue (wave per node) ----
    epilogue_kernel<<<(NN_ + 3) / 4, 256, 0, stream>>>(
        P1, P2, offs, x, hidden,
        root_xr, root_hr, root_xz, root_hz, root_xn,
        b_xr, b_hr, b_xz, b_hz, b_xn, out);
}

// Round 24
// 283.169 us; speedup vs baseline: 1.0941x; 1.0054x over previous
//
#include <hip/hip_runtime.h>
#include <math.h>

#define NN_   6000
#define EE_   192000
#define CIN_  32
#define CHID_ 64
#define KK_   125   // 5^3 spline kernel cells
#define EB_   32    // edge batch per block in build_T
#define CH1_  4     // x-GEMM outer chunks (each = CPB*64 cols)
#define CH2_  8     // h-GEMM outer chunks
#define CPB_  16    // k-chunks per GEMM block (64 cols each)

// fp32 -> bf16 round-to-nearest-even
static __device__ __forceinline__ unsigned short f2bf(float f) {
    unsigned int u = __builtin_bit_cast(unsigned int, f);
    u += 0x7fff + ((u >> 16) & 1);
    return (unsigned short)(u >> 16);
}
static __device__ __forceinline__ float bf2f(unsigned short h) {
    unsigned int u = ((unsigned int)h) << 16;
    return __builtin_bit_cast(float, u);
}

// ---------------------------------------------------------------------------
// Launch 1: deg count + weight packs (independent work, one launch).
// ---------------------------------------------------------------------------
#define PK1_ (192 * KK_ * CIN_)    // 768000
#define PK2_ (128 * KK_ * CHID_)   // 1024000
#define CB_  ((EE_ + 255) / 256)   // 750 count blocks
__global__ __launch_bounds__(256) void count_pack_kernel(
    const int* __restrict__ ei, int* __restrict__ deg,
    const float* __restrict__ W_xr, const float* __restrict__ W_xz,
    const float* __restrict__ W_xn, const float* __restrict__ W_hr,
    const float* __restrict__ W_hz,
    unsigned short* __restrict__ B1t, unsigned short* __restrict__ B2t)
{
    const int b = blockIdx.x;
    if (b < CB_) {
        int e = b * 256 + threadIdx.x;
        if (e < EE_) atomicAdd(&deg[ei[EE_ + e]], 1);
        return;
    }
    int gid = (b - CB_) * 256 + threadIdx.x;
    if (gid < PK1_) {
        int n  = gid / (KK_ * CIN_);
        int kk = gid % (KK_ * CIN_);
        int conv = n >> 6, o = n & 63;
        const float* W = (conv == 0) ? W_xr : ((conv == 1) ? W_xz : W_xn);
        B1t[gid] = f2bf(W[(size_t)kk * 64 + o]);
    } else if (gid < PK1_ + PK2_) {
        int g2 = gid - PK1_;
        int n  = g2 / (KK_ * CHID_);
        int kk = g2 % (KK_ * CHID_);
        int conv = n >> 6, o = n & 63;
        const float* W = (conv == 0) ? W_hr : W_hz;
        B2t[g2] = f2bf(W[(size_t)kk * 64 + o]);
    }
}

__global__ __launch_bounds__(1024) void scan_kernel(
    const int* __restrict__ deg, int* __restrict__ offs, int* __restrict__ cursor)
{
    __shared__ int part[1024];
    const int tid = threadIdx.x;
    const int CH = (NN_ + 1023) / 1024;   // 6
    const int base = tid * CH;
    int loc[CH];
    int s = 0;
#pragma unroll
    for (int i = 0; i < CH; ++i) {
        int v = (base + i < NN_) ? deg[base + i] : 0;
        loc[i] = s; s += v;
    }
    part[tid] = s;
    __syncthreads();
    for (int off = 1; off < 1024; off <<= 1) {
        int v = (tid >= off) ? part[tid - off] : 0;
        __syncthreads();
        part[tid] += v;
        __syncthreads();
    }
    const int pre = (tid > 0) ? part[tid - 1] : 0;
#pragma unroll
    for (int i = 0; i < CH; ++i) {
        if (base + i < NN_) {
            offs[base + i]   = pre + loc[i];
            cursor[base + i] = pre + loc[i];
        }
    }
    if (tid == 1023) offs[NN_] = part[1023];
}

// Compute per-edge spline meta ONCE, scattered to dst-sorted position.
__global__ __launch_bounds__(256) void prep_kernel(
    const int* __restrict__ ei, const float* __restrict__ attr,
    int* __restrict__ cursor, float4* __restrict__ meta_s, int* __restrict__ src_s)
{
    int e = blockIdx.x * 256 + threadIdx.x;
    if (e >= EE_) return;
    const int dst = ei[EE_ + e];
    const int p   = atomicAdd(&cursor[dst], 1);
    float f[3]; int i0[3];
#pragma unroll
    for (int d = 0; d < 3; ++d) {
        float u  = attr[e * 3 + d] * 4.0f;
        float fl = floorf(u);
        fl = fminf(fmaxf(fl, 0.0f), 3.0f);
        i0[d] = (int)fl;
        f[d]  = u - fl;
    }
    meta_s[p] = make_float4(f[0], f[1], f[2],
        __int_as_float(i0[0] * 25 + i0[1] * 5 + i0[2]));
    src_s[p] = ei[e];
}

// ---------------------------------------------------------------------------
// Per-node T build v3 (R22-proven): phase 1 precomputes the 8 basis products
// per edge so phase 3 reads p = s_basis[e*8+s_c] (8-lane broadcast) instead
// of recomputing. Non-atomic b64 LDS RMW; packed-bf16 feat staging.
// Separate kernels per C so the LDS arena is per-C sized.
// ---------------------------------------------------------------------------
template<int C>
__global__ __launch_bounds__(256) void build_T_kernel(
    const float4* __restrict__ meta_s, const int* __restrict__ src_s,
    const float* __restrict__ feat, const int* __restrict__ offs,
    unsigned short* __restrict__ Tb)
{
    constexpr int PAD   = C + 2;
    constexpr int NPAIR = C / 2;
    constexpr int EPI   = (C == 32) ? 2 : 1;     // edges per iteration
    constexpr int PPW   = (C == 32) ? 4 : 8;     // pairs owned per wave
    __shared__ float        Tl[KK_ * PAD];
    __shared__ int          s_base[EB_];
    __shared__ float        s_basis[EB_ * 8];
    __shared__ int          s_src[EB_];
    __shared__ unsigned int s_fb[EB_ * NPAIR];   // packed bf16 pairs

    const int node = blockIdx.x;
    const int tid  = threadIdx.x;
    const int wave = tid >> 6;
    const int lane = tid & 63;

    for (int i = tid; i < KK_ * PAD; i += 256) Tl[i] = 0.f;

    const int j0 = offs[node], j1 = offs[node + 1];

    const int e2   = (EPI == 2) ? (lane >> 5) : 0;
    const int s_c  = (EPI == 2) ? ((lane >> 2) & 7) : (lane >> 3);
    const int pl   = (EPI == 2) ? (lane & 3) : (lane & 7);
    const int pidx = wave * PPW + pl;
    const int cb0 = s_c & 1, cb1 = (s_c >> 1) & 1, cb2 = (s_c >> 2) & 1;
    const int offc = cb0 * 25 + cb1 * 5 + cb2;

    __syncthreads();

    for (int jb = j0; jb < j1; jb += EB_) {
        const int m = min(EB_, j1 - jb);

        // phase 1: load edge records; precompute base + all 8 basis products
        if (tid < m) {
            const float4 mt = meta_s[jb + tid];
            s_src[tid]  = src_s[jb + tid];
            s_base[tid] = __float_as_int(mt.w);
            const float f0 = mt.x, f1 = mt.y, f2 = mt.z;
            const float g0 = 1.f - f0, g1 = 1.f - f1, g2 = 1.f - f2;
            float4 blo = make_float4(g0 * g1 * g2, f0 * g1 * g2,
                                     g0 * f1 * g2, f0 * f1 * g2);
            float4 bhi = make_float4(g0 * g1 * f2, f0 * g1 * f2,
                                     g0 * f1 * f2, f0 * f1 * f2);
            *(float4*)&s_basis[tid * 8]     = blo;
            *(float4*)&s_basis[tid * 8 + 4] = bhi;
        }
        __syncthreads();

        // phase 2: gather feature rows -> packed bf16 in LDS
        for (int u = tid; u < m * NPAIR; u += 256) {
            const int r = u / NPAIR, q = u % NPAIR;
            float2 v = *(const float2*)&feat[(size_t)s_src[r] * C + 2 * q];
            s_fb[u] = (unsigned int)f2bf(v.x) | ((unsigned int)f2bf(v.y) << 16);
        }
        __syncthreads();

        // phase 3: race-free LDS accumulate (basis/base read, not recomputed)
        for (int eb = 0; eb < m; eb += EPI) {
            const int e = eb + e2;
            if (EPI == 1 || e < m) {
                const int   base = s_base[e];
                const float p    = s_basis[e * 8 + s_c];
                const unsigned int fp = s_fb[e * NPAIR + pidx];
                const float fx = bf2f((unsigned short)(fp & 0xffff));
                const float fy = bf2f((unsigned short)(fp >> 16));
                float* cell = &Tl[(base + offc) * PAD + 2 * pidx];
                cell[0] += p * fx;
                cell[1] += p * fy;
            }
        }
        __syncthreads();
    }

    unsigned int* To = (unsigned int*)(Tb + (size_t)node * (KK_ * C));
    for (int u = tid; u < KK_ * NPAIR; u += 256) {
        int k = u / NPAIR, pp = u % NPAIR;
        unsigned int lo = f2bf(Tl[k * PAD + 2 * pp]);
        unsigned int hi = f2bf(Tl[k * PAD + 2 * pp + 1]);
        To[u] = lo | (hi << 16);
    }
}

// ---------------------------------------------------------------------------
// GEMM body v7 (R21-proven): COLS=64, CPB=16, barrier-free inner loop,
// A-frags per-lane direct from global, no cross-chunk prefetch (R19 lesson).
// ---------------------------------------------------------------------------
template<int NT, int NTF, int CPB>
static __device__ __forceinline__ void gemm_body(
    unsigned char* arena,
    const unsigned short* __restrict__ A, const unsigned short* __restrict__ Bt,
    unsigned short* __restrict__ P, int M, int Kd, int chunk, int zhalf)
{
    constexpr int SPC   = 2;
    constexpr int COLS  = SPC * 32;       // 64
    constexpr int BP    = COLS + 8;       // 72 shorts
    constexpr int NFRAG = NT / 16;
    constexpr int CSP   = NT + 8;
    unsigned short (*Bs)[BP] = (unsigned short(*)[BP])arena;

    using bf16x8 = __attribute__((ext_vector_type(8))) short;
    using f32x4  = __attribute__((ext_vector_type(4))) float;

    const int tid  = threadIdx.x;
    const int wave = tid >> 6;
    const int lane = tid & 63;
    const int quad = lane >> 4;
    const int l16  = lane & 15;
    const int m0   = blockIdx.x * 64;
    const unsigned short* Bp = Bt + (size_t)zhalf * NT * Kd;

    const int  arow   = m0 + wave * 16 + l16;
    const bool avalid = arow < M;
    const unsigned short* Ap = A + (size_t)(avalid ? arow : 0) * Kd;

    f32x4 acc[NFRAG];
#pragma unroll
    for (int f = 0; f < NFRAG; ++f) acc[f] = (f32x4){0.f, 0.f, 0.f, 0.f};

    for (int cc = 0; cc < CPB; ++cc) {
        const int k0 = (chunk * CPB + cc) * COLS;
        if (k0 >= Kd) break;
        const int ksz = min(Kd - k0, COLS);

        __syncthreads();

        constexpr int BUNITS = NT * COLS / 8;
        for (int u = tid; u < BUNITS; u += 256) {
            const int row = u / (COLS / 8);
            const int cq  = (u % (COLS / 8)) * 8;
            uint4 v = make_uint4(0u, 0u, 0u, 0u);
            if (cq < ksz) v = *(const uint4*)(Bp + (size_t)row * Kd + k0 + cq);
            *(uint4*)&Bs[row][cq] = v;
        }

        uint4 afr[SPC];
#pragma unroll
        for (int s = 0; s < SPC; ++s) {
            const int k = k0 + s * 32 + quad * 8;
            afr[s] = (avalid && k < Kd) ? *(const uint4*)(Ap + k)
                                        : make_uint4(0u, 0u, 0u, 0u);
        }

        __syncthreads();

#pragma unroll
        for (int s = 0; s < SPC; ++s) {
            bf16x8 af = __builtin_bit_cast(bf16x8, afr[s]);
#pragma unroll
            for (int f = 0; f < NFRAG; ++f) {
                bf16x8 bfv = *(bf16x8*)&Bs[f * 16 + l16][s * 32 + quad * 8];
                acc[f] = __builtin_amdgcn_mfma_f32_16x16x32_bf16(af, bfv, acc[f], 0, 0, 0);
            }
        }
    }

    __syncthreads();
    unsigned short* Cs = (unsigned short*)arena;   // [64][CSP]
    const int rbase = wave * 16 + quad * 4;
#pragma unroll
    for (int f = 0; f < NFRAG; ++f) {
        const int col = f * 16 + l16;
#pragma unroll
        for (int r = 0; r < 4; ++r)
            Cs[(rbase + r) * CSP + col] = f2bf(acc[f][r]);
    }
    __syncthreads();
    unsigned short* Pc = P + ((size_t)chunk * M + m0) * NTF + zhalf * NT;
    constexpr int UNITS = 64 * NT / 8;
    for (int u = tid; u < UNITS; u += 256) {
        const int row = (u * 8) / NT, col = (u * 8) % NT;
        if (m0 + row < M)
            *(uint4*)&Pc[(size_t)row * NTF + col] = *(const uint4*)&Cs[row * CSP + col];
    }
}

// Merged GEMM: blockIdx.y < CH2_ -> h-chunk; else x-(chunk,half).
__global__ __launch_bounds__(256) void gemm_all_kernel(
    const unsigned short* __restrict__ Tx, const unsigned short* __restrict__ B1t,
    unsigned short* __restrict__ P1,
    const unsigned short* __restrict__ Th, const unsigned short* __restrict__ B2t,
    unsigned short* __restrict__ P2)
{
    __shared__ __align__(16) unsigned char arena[128 * 72 * 2];
    const int y = blockIdx.y;
    if (y < CH2_) {
        gemm_body<128, 128, CPB_>(arena, Th, B2t, P2, NN_, KK_ * CHID_, y, 0);
    } else {
        const int g = y - CH2_;            // 0..7 -> (chunk 0..3, half 0..1)
        gemm_body<96, 192, CPB_>(arena, Tx, B1t, P1, NN_, KK_ * CIN_, g >> 1, g & 1);
    }
}

// ---------------------------------------------------------------------------
// Epilogue: one wave per node, lane = output channel. Sums bf16 split-K
// partials (L2-resident), mean-agg, root GEMV, GRU gates.
// ---------------------------------------------------------------------------
__global__ __launch_bounds__(256) void epilogue_kernel(
    const unsigned short* __restrict__ P1, const unsigned short* __restrict__ P2,
    const int* __restrict__ offs,
    const float* __restrict__ x, const float* __restrict__ hidden,
    const float* __restrict__ root_xr, const float* __restrict__ root_hr,
    const float* __restrict__ root_xz, const float* __restrict__ root_hz,
    const float* __restrict__ root_xn,
    const float* __restrict__ b_xr, const float* __restrict__ b_hr,
    const float* __restrict__ b_xz, const float* __restrict__ b_hz,
    const float* __restrict__ b_xn,
    float* __restrict__ out)
{
    __shared__ float xsh[4][32];
    __shared__ float hsh[4][64];
    const int w = threadIdx.x >> 6;
    const int o = threadIdx.x & 63;
    const int m = blockIdx.x * 4 + w;
    if (m >= NN_) return;

    if (o < 32) xsh[w][o] = x[(size_t)m * 32 + o];
    const float hval = hidden[(size_t)m * 64 + o];
    hsh[w][o] = hval;

    float axr = 0.f, axz = 0.f, axn = 0.f;
#pragma unroll
    for (int c = 0; c < CH1_; ++c) {
        const unsigned short* p = P1 + ((size_t)c * NN_ + m) * 192;
        axr += bf2f(p[o]); axz += bf2f(p[64 + o]); axn += bf2f(p[128 + o]);
    }
    float ahr = 0.f, ahz = 0.f;
#pragma unroll
    for (int c = 0; c < CH2_; ++c) {
        const unsigned short* p = P2 + ((size_t)c * NN_ + m) * 128;
        ahr += bf2f(p[o]); ahz += bf2f(p[64 + o]);
    }

    const int   dg   = offs[m + 1] - offs[m];
    const float dinv = 1.0f / fmaxf((float)dg, 1.0f);
    axr *= dinv; axz *= dinv; axn *= dinv; ahr *= dinv; ahz *= dinv;

    float sxr = 0.f, sxz = 0.f, sxn = 0.f;
#pragma unroll
    for (int c = 0; c < CIN_; ++c) {
        float xv = xsh[w][c];
        sxr += xv * root_xr[c * 64 + o];
        sxz += xv * root_xz[c * 64 + o];
        sxn += xv * root_xn[c * 64 + o];
    }
    float shr = 0.f, shz = 0.f;
#pragma unroll
    for (int c = 0; c < CHID_; ++c) {
        float hv = hsh[w][c];
        shr += hv * root_hr[c * 64 + o];
        shz += hv * root_hz[c * 64 + o];
    }

    const float conv_xr = axr + sxr + b_xr[o];
    const float conv_xz = axz + sxz + b_xz[o];
    const float conv_xn = axn + sxn + b_xn[o];
    const float hr_out  = ahr + shr + b_hr[o];
    const float conv_hz = ahz + shz + b_hz[o];

    const float rg = 1.0f / (1.0f + expf(-(conv_xr + hr_out)));
    const float zg = 1.0f / (1.0f + expf(-(conv_xz + conv_hz)));
    const float ng = tanhf(conv_xn + rg * hr_out);
    out[(size_t)m * 64 + o] = (1.0f - zg) * ng + zg * hval;
}

// ---------------------------------------------------------------------------
extern "C" void kernel_launch(void* const* d_in, const int* in_sizes, int n_in,
                              void* d_out, int out_size, void* d_ws, size_t ws_size,
                              hipStream_t stream)
{
    const float* x       = (const float*)d_in[0];
    const float* hidden  = (const float*)d_in[1];
    const int*   ei      = (const int*)  d_in[2];
    const float* attr    = (const float*)d_in[3];
    const float* W_xr    = (const float*)d_in[4];
    const float* root_xr = (const float*)d_in[5];
    const float* b_xr    = (const float*)d_in[6];
    const float* W_hr    = (const float*)d_in[7];
    const float* root_hr = (const float*)d_in[8];
    const float* b_hr    = (const float*)d_in[9];
    const float* W_xz    = (const float*)d_in[10];
    const float* root_xz = (const float*)d_in[11];
    const float* b_xz    = (const float*)d_in[12];
    const float* W_hz    = (const float*)d_in[13];
    const float* root_hz = (const float*)d_in[14];
    const float* b_hz    = (const float*)d_in[15];
    const float* W_xn    = (const float*)d_in[16];
    const float* root_xn = (const float*)d_in[17];
    const float* b_xn    = (const float*)d_in[18];
    // d_in[19..21] (W_hn/root_hn/b_hn) are dead: reference reuses hr_out.
    float* out = (float*)d_out;

    // Workspace (~175 MB). No aliasing (gemm-x reads Tx while gemm-h writes
    // P2 concurrently inside gemm_all).
    char* w = (char*)d_ws;
    unsigned short* Tx  = (unsigned short*)w; w += (size_t)NN_ * KK_ * CIN_  * 2;  // 48 MB
    unsigned short* Th  = (unsigned short*)w; w += (size_t)NN_ * KK_ * CHID_ * 2;  // 96 MB
    unsigned short* B1t = (unsigned short*)w; w += (size_t)192 * KK_ * CIN_  * 2;  // 1.5 MB
    unsigned short* B2t = (unsigned short*)w; w += (size_t)128 * KK_ * CHID_ * 2;  // 2.0 MB
    unsigned short* P1  = (unsigned short*)w; w += (size_t)CH1_ * NN_ * 192 * 2;   // 9.2 MB
    unsigned short* P2  = (unsigned short*)w; w += (size_t)CH2_ * NN_ * 128 * 2;   // 12.3 MB
    float4* meta_s = (float4*)w; w += (size_t)EE_ * 16;                            // 3.07 MB
    int* src_s  = (int*)w;   w += (size_t)EE_ * 4;                                 // 0.77 MB
    int* deg    = (int*)w;   w += (size_t)NN_ * 4;
    int* offs   = (int*)w;   w += (size_t)(NN_ + 4) * 4;
    int* cursor = (int*)w;   w += (size_t)NN_ * 4;

    const int MT = (NN_ + 63) / 64;   // 94 m-tiles

    hipMemsetAsync(deg, 0, (size_t)NN_ * 4, stream);

    // ---- launch 1: deg count + weight packs (independent, merged) ----
    const int PACKB = (PK1_ + PK2_ + 255) / 256;
    count_pack_kernel<<<CB_ + PACKB, 256, 0, stream>>>(
        ei, deg, W_xr, W_xz, W_xn, W_hr, W_hz, B1t, B2t);

    // ---- scan + sorted edge records ----
    scan_kernel<<<1, 1024, 0, stream>>>(deg, offs, cursor);
    prep_kernel<<<(EE_ + 255) / 256, 256, 0, stream>>>(ei, attr, cursor, meta_s, src_s);

    // ---- T builds: separate kernels so LDS arena is per-C sized ----
    build_T_kernel<CHID_><<<NN_, 256, 0, stream>>>(meta_s, src_s, hidden, offs, Th);
    build_T_kernel<CIN_><<<NN_, 256, 0, stream>>>(meta_s, src_s, x, offs, Tx);

    // ---- merged x+h GEMMs (co-resident, one launch) ----
    gemm_all_kernel<<<dim3(MT, CH2_ + 2 * CH1_), 256, 0, stream>>>(
        Tx, B1t, P1, Th, B2t, P2);

    // ---- fused reduce + GRU epilogue (wave per node) ----
    epilogue_kernel<<<(NN_ + 3) / 4, 256, 0, stream>>>(
        P1, P2, offs, x, hidden,
        root_xr, root_hr, root_xz, root_hz, root_xn,
        b_xr, b_hr, b_xz, b_hz, b_xn, out);
}